// Round 1
// baseline (1537.179 us; speedup 1.0000x reference)
//
#include <hip/hip_runtime.h>
#include <hip/hip_bf16.h>

#define NN   20000
#define HIDD 128
#define E1N  100000
#define E2N  100000
#define NEFF (E1N + NN + E2N)   /* 220000 effective edges (skip row>=n half of E3d) */
#define TILE 32

__device__ __forceinline__ float4 ld4(const float* p) {
    return *reinterpret_cast<const float4*>(p);
}

// rbf_expand: centers = linspace(0,6,64) -> step 6/63; width = 6/64
// env = 0.5*(cos(pi*clip(d/6,0,1))+1); rbf_k = exp(-(d-c_k)^2/(2w^2)) * env
__device__ __forceinline__ float rbf_val(float d, int k) {
    const float step = 0.09523809523809523f;   // 6/63
    const float inv2w2 = 56.88888888888889f;   // 1/(2*(6/64)^2)
    float c = (float)k * step;
    float t = d - c;
    float x = d * (1.0f / 6.0f);
    x = fminf(fmaxf(x, 0.0f), 1.0f);
    float env = 0.5f * (__cosf(3.14159265358979f * x) + 1.0f);
    return __expf(-t * t * inv2w2) * env;
}

// ---------------- kernel 1: nodes = concat([H||H2d, H||virt]) @ W_i.T ----------------
__global__ __launch_bounds__(256) void nodes_kernel(
    const float* __restrict__ H, const float* __restrict__ H2d,
    const float* __restrict__ virt, const float* __restrict__ Wi,
    float* __restrict__ nodes) {
    __shared__ float x[16][256];
    const int t = threadIdx.x;
    const int rbase = blockIdx.x * 16;

    for (int i = t; i < 16 * 64; i += 256) {
        int r = i >> 6, q = i & 63;
        int row = rbase + r;
        float4 v;
        if (row < NN) {
            v = (q < 32) ? ld4(H + row * 128 + q * 4) : ld4(H2d + row * 128 + (q - 32) * 4);
        } else {
            int rr = row - NN;
            v = (q < 32) ? ld4(H + rr * 128 + q * 4) : ld4(virt + (q - 32) * 4);
        }
        *reinterpret_cast<float4*>(&x[r][q * 4]) = v;
    }
    __syncthreads();

    const int j = t & 127;
    const int rg = t >> 7;   // 0/1 -> rows rg*8 .. rg*8+7
    float acc[8] = {0.f, 0.f, 0.f, 0.f, 0.f, 0.f, 0.f, 0.f};
    for (int k4 = 0; k4 < 64; ++k4) {
        float4 w = ld4(Wi + j * 256 + k4 * 4);
#pragma unroll
        for (int r = 0; r < 8; ++r) {
            float4 xv = *reinterpret_cast<const float4*>(&x[rg * 8 + r][k4 * 4]);
            acc[r] += w.x * xv.x + w.y * xv.y + w.z * xv.z + w.w * xv.w;
        }
    }
#pragma unroll
    for (int r = 0; r < 8; ++r)
        nodes[(rbase + rg * 8 + r) * 128 + j] = acc[r];
}

// ---------------- kernel 2: fused per-edge pipeline ----------------
__global__ __launch_bounds__(256, 2) void edge_kernel(
    const float* __restrict__ nodes, const float* __restrict__ V,
    const float* __restrict__ Z, const float* __restrict__ Z3d,
    const int* __restrict__ E2d_idx, const float* __restrict__ E2d_feat,
    const int* __restrict__ Edist_idx, const float* __restrict__ Edist_val,
    const float* __restrict__ et_embed,
    const float* __restrict__ W_rbf, const float* __restrict__ W_e2d,
    const float* __restrict__ W_phi1, const float* __restrict__ b_phi1,
    const float* __restrict__ W_phi2, const float* __restrict__ b_phi2,
    const float* __restrict__ W_msg, const float* __restrict__ b_msg,
    float* __restrict__ Hout, float* __restrict__ Vout) {

    // LDS budget kept under 64KB: phi_in 37376 + hid_pre 16896 + rbfd 8704 + misc ~1KB
    __shared__ float phi_in[TILE][292];   // stride 292: 1168B, 16B-aligned rows
    __shared__ float hid_pre[TILE][132];  // union: 'pre'[64] in phase A, 'hid'[128] in B/C
    __shared__ float rbfd[TILE][68];
    __shared__ int   s_row[TILE], s_col[TILE], s_vcol[TILE];
    __shared__ float s_unit[TILE][3];
    __shared__ float s_dist[TILE], s_dval[TILE];

    const int t = threadIdx.x;
    const int gbase = blockIdx.x * TILE;
    // all type boundaries (100000, 120000) are multiples of 32 -> block-uniform type
    const int btype = (gbase < E1N) ? 0 : ((gbase < E1N + NN) ? 1 : 2);

    // ---- setup: edge meta ----
    if (t < TILE) {
        int eid = gbase + t;
        int row, col;
        float dval = 0.f;
        if (btype == 0) {
            row = E2d_idx[eid];
            col = E2d_idx[E1N + eid];
        } else if (btype == 1) {
            int jj = eid - E1N;
            row = jj;
            col = jj + NN;
        } else {
            int g = eid - E1N - NN;
            row = Edist_idx[g];
            col = Edist_idx[E2N + g];
            dval = Edist_val[g];
        }
        float prx = Z[row * 3], pry = Z[row * 3 + 1], prz = Z[row * 3 + 2];
        float pcx, pcy, pcz;
        if (col < NN) {
            pcx = Z[col * 3]; pcy = Z[col * 3 + 1]; pcz = Z[col * 3 + 2];
        } else {
            int c = col - NN;
            pcx = Z3d[c * 3]; pcy = Z3d[c * 3 + 1]; pcz = Z3d[c * 3 + 2];
        }
        float dx = prx - pcx, dy = pry - pcy, dz = prz - pcz;
        float dist = sqrtf(dx * dx + dy * dy + dz * dz + 1e-8f);
        float inv = 1.0f / dist;
        s_row[t] = row;
        s_col[t] = col;
        s_vcol[t] = (col < NN) ? col : -1;  // v[col]=0 for virtual cols
        s_unit[t][0] = dx * inv; s_unit[t][1] = dy * inv; s_unit[t][2] = dz * inv;
        s_dist[t] = dist;
        s_dval[t] = dval;
    }
    __syncthreads();

    // ---- phase A: fill phi_in[0:128] (nodes[col]), [256:288] (edge-type embed),
    //      rbfd (rbf of geometric dist, all types), pre (type0 feat / type2 rbf) ----
    for (int i = t; i < TILE * 32; i += 256) {
        int e = i >> 5, q = i & 31;
        *reinterpret_cast<float4*>(&phi_in[e][q * 4]) = ld4(nodes + s_col[e] * 128 + q * 4);
    }
    for (int i = t; i < TILE * 32; i += 256) {
        int e = i >> 5, q = i & 31;
        phi_in[e][256 + q] = et_embed[btype * 32 + q];
    }
    for (int i = t; i < TILE * 64; i += 256) {
        int e = i & 31, k = i >> 5;   // lanes consecutive in e -> coalesced feat gather
        rbfd[e][k] = rbf_val(s_dist[e], k);
        if (btype == 0)      hid_pre[e][k] = E2d_feat[k * E1N + gbase + e];
        else if (btype == 2) hid_pre[e][k] = rbf_val(s_dval[e], k);
    }
    __syncthreads();

    const int j = t & 127;
    const int eg = t >> 7;
    const int ebase = eg * 16;

    // ---- attr: phi_in[:,128:256] = pre @ W.T  (W = W_e2d | 0 | W_rbf) ----
    if (btype == 1) {
#pragma unroll
        for (int i = 0; i < 16; ++i) phi_in[ebase + i][128 + j] = 0.f;
    } else {
        const float* W = (btype == 0) ? W_e2d : W_rbf;   // both (128,64) row-major
        float a[16];
#pragma unroll
        for (int i = 0; i < 16; ++i) a[i] = 0.f;
        for (int k4 = 0; k4 < 16; ++k4) {
            float4 w = ld4(W + j * 64 + k4 * 4);
#pragma unroll
            for (int i = 0; i < 16; ++i) {
                float4 p = *reinterpret_cast<const float4*>(&hid_pre[ebase + i][k4 * 4]);
                a[i] += w.x * p.x + w.y * p.y + w.z * p.z + w.w * p.w;
            }
        }
#pragma unroll
        for (int i = 0; i < 16; ++i) phi_in[ebase + i][128 + j] = a[i];
    }
    __syncthreads();

    // ---- phase B: hid = silu(phi_in @ W_phi1.T + b1)  (K=288) ----
    {
        float acc[16];
#pragma unroll
        for (int i = 0; i < 16; ++i) acc[i] = b_phi1[j];
        for (int k4 = 0; k4 < 72; ++k4) {
            float4 w = ld4(W_phi1 + j * 288 + k4 * 4);
#pragma unroll
            for (int i = 0; i < 16; ++i) {
                float4 p = *reinterpret_cast<const float4*>(&phi_in[ebase + i][k4 * 4]);
                acc[i] += w.x * p.x + w.y * p.y + w.z * p.z + w.w * p.w;
            }
        }
        __syncthreads();  // pre-buffer dead; safe to overwrite with hid
#pragma unroll
        for (int i = 0; i < 16; ++i) {
            float xv = acc[i];
            hid_pre[ebase + i][j] = xv / (1.0f + __expf(-xv));
        }
    }
    __syncthreads();

    // ---- phase C: phi2 (128->384), wd (64->384), m = phi*wd, scatter ----
    const int d = j;
    float P0[16], P1[16], P2[16];
#pragma unroll
    for (int i = 0; i < 16; ++i) {
        P0[i] = b_phi2[d]; P1[i] = b_phi2[128 + d]; P2[i] = b_phi2[256 + d];
    }
    for (int k4 = 0; k4 < 32; ++k4) {
        float4 w0 = ld4(W_phi2 + (size_t)d * 128 + k4 * 4);
        float4 w1 = ld4(W_phi2 + (size_t)(128 + d) * 128 + k4 * 4);
        float4 w2 = ld4(W_phi2 + (size_t)(256 + d) * 128 + k4 * 4);
#pragma unroll
        for (int i = 0; i < 16; ++i) {
            float4 h = *reinterpret_cast<const float4*>(&hid_pre[ebase + i][k4 * 4]);
            P0[i] += w0.x * h.x + w0.y * h.y + w0.z * h.z + w0.w * h.w;
            P1[i] += w1.x * h.x + w1.y * h.y + w1.z * h.z + w1.w * h.w;
            P2[i] += w2.x * h.x + w2.y * h.y + w2.z * h.z + w2.w * h.w;
        }
    }
    float G0[16], G1[16], G2[16];
#pragma unroll
    for (int i = 0; i < 16; ++i) {
        G0[i] = b_msg[d]; G1[i] = b_msg[128 + d]; G2[i] = b_msg[256 + d];
    }
    for (int k4 = 0; k4 < 16; ++k4) {
        float4 w0 = ld4(W_msg + d * 64 + k4 * 4);
        float4 w1 = ld4(W_msg + (128 + d) * 64 + k4 * 4);
        float4 w2 = ld4(W_msg + (256 + d) * 64 + k4 * 4);
#pragma unroll
        for (int i = 0; i < 16; ++i) {
            float4 r = *reinterpret_cast<const float4*>(&rbfd[ebase + i][k4 * 4]);
            G0[i] += w0.x * r.x + w0.y * r.y + w0.z * r.z + w0.w * r.w;
            G1[i] += w1.x * r.x + w1.y * r.y + w1.z * r.z + w1.w * r.w;
            G2[i] += w2.x * r.x + w2.y * r.y + w2.z * r.z + w2.w * r.w;
        }
    }
#pragma unroll
    for (int i = 0; i < 16; ++i) {
        int e = ebase + i;
        float sm = P0[i] * G0[i];   // s_msg[d]
        float vg = P1[i] * G1[i];   // v_gate[d]
        float rg = P2[i] * G2[i];   // r_gate[d]
        int row = s_row[e];
        unsafeAtomicAdd(&Hout[(size_t)row * 128 + d], sm);
        int vc = s_vcol[e];
        float vx = 0.f, vy = 0.f, vz = 0.f;
        if (vc >= 0) {
            const float* vp = V + ((size_t)vc * 128 + d) * 3;
            vx = vp[0]; vy = vp[1]; vz = vp[2];
        }
        float* vo = Vout + ((size_t)row * 128 + d) * 3;
        unsafeAtomicAdd(vo + 0, vx * vg + s_unit[e][0] * rg);
        unsafeAtomicAdd(vo + 1, vy * vg + s_unit[e][1] * rg);
        unsafeAtomicAdd(vo + 2, vz * vg + s_unit[e][2] * rg);
    }
}

extern "C" void kernel_launch(void* const* d_in, const int* in_sizes, int n_in,
                              void* d_out, int out_size, void* d_ws, size_t ws_size,
                              hipStream_t stream) {
    const float* H         = (const float*)d_in[0];
    const float* V         = (const float*)d_in[1];
    const float* Z         = (const float*)d_in[2];
    const float* H2d       = (const float*)d_in[4];
    const int*   E2d_idx   = (const int*)d_in[6];
    const float* E2d_feat  = (const float*)d_in[7];
    const float* Z3d       = (const float*)d_in[8];
    const int*   Edist_idx = (const int*)d_in[10];
    const float* Edist_val = (const float*)d_in[11];
    const float* virt      = (const float*)d_in[12];
    const float* et        = (const float*)d_in[13];
    const float* W_rbf     = (const float*)d_in[14];
    const float* W_e2d     = (const float*)d_in[15];
    const float* W_i       = (const float*)d_in[16];
    const float* W_phi1    = (const float*)d_in[17];
    const float* b_phi1    = (const float*)d_in[18];
    const float* W_phi2    = (const float*)d_in[19];
    const float* b_phi2    = (const float*)d_in[20];
    const float* W_msg     = (const float*)d_in[21];
    const float* b_msg     = (const float*)d_in[22];

    float* nodes = (float*)d_ws;                 // 40000 x 128 f32 = 20.48 MB
    float* Hout  = (float*)d_out;                // (N,128)
    float* Vout  = Hout + (size_t)NN * 128;      // (N,128,3)

    hipMemsetAsync(d_out, 0, (size_t)out_size * sizeof(float), stream);
    nodes_kernel<<<(2 * NN) / 16, 256, 0, stream>>>(H, H2d, virt, W_i, nodes);
    edge_kernel<<<NEFF / TILE, 256, 0, stream>>>(
        nodes, V, Z, Z3d, E2d_idx, E2d_feat, Edist_idx, Edist_val, et,
        W_rbf, W_e2d, W_phi1, b_phi1, W_phi2, b_phi2, W_msg, b_msg, Hout, Vout);
}

// Round 2
// 1069.376 us; speedup vs baseline: 1.4375x; 1.4375x over previous
//
#include <hip/hip_runtime.h>
#include <hip/hip_bf16.h>

#define NN   20000
#define E1N  100000
#define E2N  100000
#define NEFF (E1N + NN + E2N)   /* 220000 effective edges */
#define TILE 64

typedef short  bf16x8 __attribute__((ext_vector_type(8)));
typedef float  f32x4  __attribute__((ext_vector_type(4)));

__device__ __forceinline__ float4 ld4(const float* p) {
    return *reinterpret_cast<const float4*>(p);
}
__device__ __forceinline__ ushort f2bf(float x) {
    __hip_bfloat16 h = __float2bfloat16(x);
    return *reinterpret_cast<ushort*>(&h);
}

// rbf_expand: centers = linspace(0,6,64) -> step 6/63; width = 6/64
__device__ __forceinline__ float rbf_val(float d, int k) {
    const float step = 0.09523809523809523f;   // 6/63
    const float inv2w2 = 56.88888888888889f;   // 1/(2*(6/64)^2)
    float c = (float)k * step;
    float t = d - c;
    float x = d * (1.0f / 6.0f);
    x = fminf(fmaxf(x, 0.0f), 1.0f);
    float env = 0.5f * (__cosf(3.14159265358979f * x) + 1.0f);
    return __expf(-t * t * inv2w2) * env;
}

// ---------------- prep: folded/bf16 weights ----------------
// W1c (128,256) bf16 = [W_phi1[:,:128] | W_phi1[:,128:256]@W_e2d | W_phi1[:,128:256]@W_rbf]
// b_type (3,128) f32 = b_phi1 + W_phi1[:,256:288] @ et[ty]
__global__ __launch_bounds__(256) void prep_kernel(
    const float* __restrict__ W_phi1, const float* __restrict__ b_phi1,
    const float* __restrict__ W_e2d, const float* __restrict__ W_rbf,
    const float* __restrict__ W_phi2, const float* __restrict__ W_msg,
    const float* __restrict__ et,
    ushort* __restrict__ W1c, ushort* __restrict__ W2b,
    ushort* __restrict__ Wmb, float* __restrict__ b_type) {
    int g = blockIdx.x * 256 + threadIdx.x;
    if (g < 32768) {
        int n = g >> 8, k = g & 255;
        float v;
        if (k < 128) v = W_phi1[n * 288 + k];
        else {
            int kk = k - 128;
            const float* Wsel = (kk < 64) ? W_e2d : W_rbf;  // both (128,64)
            int j = kk & 63;
            float s = 0.f;
            for (int a = 0; a < 128; ++a) s += W_phi1[n * 288 + 128 + a] * Wsel[a * 64 + j];
            v = s;
        }
        W1c[n * 256 + k] = f2bf(v);
    } else if (g < 32768 + 49152) {
        int q = g - 32768; W2b[q] = f2bf(W_phi2[q]);
    } else if (g < 32768 + 49152 + 24576) {
        int q = g - 81920; Wmb[q] = f2bf(W_msg[q]);
    } else if (g < 32768 + 49152 + 24576 + 384) {
        int q = g - 106496; int ty = q >> 7, n = q & 127;
        float s = b_phi1[n];
        for (int a = 0; a < 32; ++a) s += W_phi1[n * 288 + 256 + a] * et[ty * 32 + a];
        b_type[q] = s;
    }
}

// ---------------- kernel 1: nodes (bf16 out) ----------------
__global__ __launch_bounds__(256) void nodes_kernel(
    const float* __restrict__ H, const float* __restrict__ H2d,
    const float* __restrict__ virt, const float* __restrict__ Wi,
    ushort* __restrict__ nodesb) {
    __shared__ float x[16][256];
    const int t = threadIdx.x;
    const int rbase = blockIdx.x * 16;

    for (int i = t; i < 16 * 64; i += 256) {
        int r = i >> 6, q = i & 63;
        int row = rbase + r;
        float4 v;
        if (row < NN) {
            v = (q < 32) ? ld4(H + row * 128 + q * 4) : ld4(H2d + row * 128 + (q - 32) * 4);
        } else {
            int rr = row - NN;
            v = (q < 32) ? ld4(H + rr * 128 + q * 4) : ld4(virt + (q - 32) * 4);
        }
        *reinterpret_cast<float4*>(&x[r][q * 4]) = v;
    }
    __syncthreads();

    const int j = t & 127;
    const int rg = t >> 7;
    float acc[8] = {0.f, 0.f, 0.f, 0.f, 0.f, 0.f, 0.f, 0.f};
    for (int k4 = 0; k4 < 64; ++k4) {
        float4 w = ld4(Wi + j * 256 + k4 * 4);
#pragma unroll
        for (int r = 0; r < 8; ++r) {
            float4 xv = *reinterpret_cast<const float4*>(&x[rg * 8 + r][k4 * 4]);
            acc[r] += w.x * xv.x + w.y * xv.y + w.z * xv.z + w.w * xv.w;
        }
    }
#pragma unroll
    for (int r = 0; r < 8; ++r)
        nodesb[(rbase + rg * 8 + r) * 128 + j] = f2bf(acc[r]);
}

// ---------------- kernel 2: fused MFMA edge pipeline ----------------
__global__ __launch_bounds__(256, 3) void edge_kernel(
    const ushort* __restrict__ nodesb, const float* __restrict__ V,
    const float* __restrict__ Z, const float* __restrict__ Z3d,
    const int* __restrict__ E2d_idx, const float* __restrict__ E2d_feat,
    const int* __restrict__ Edist_idx, const float* __restrict__ Edist_val,
    const ushort* __restrict__ W1c, const ushort* __restrict__ W2b,
    const ushort* __restrict__ Wmb, const float* __restrict__ b_type,
    const float* __restrict__ b_phi2, const float* __restrict__ b_msg,
    float* __restrict__ Hout, float* __restrict__ Vout) {

    __shared__ ushort A1[TILE][264];    // phi1 input K=256 (+8 pad); later aliased as hid[64][136]
    __shared__ ushort rbfd[TILE][72];   // rbf(dist) K=64 (+8 pad)
    __shared__ float  s_bt[3][128];
    __shared__ int    s_row[TILE], s_col[TILE], s_vcol[TILE], s_type[TILE];
    __shared__ float  s_unit[TILE][3], s_dist[TILE], s_dval[TILE];

    ushort (*hid)[136] = reinterpret_cast<ushort(*)[136]>(&A1[0][0]);  // 8704 <= 16896 ushorts

    const int t = threadIdx.x;
    const int gbase = blockIdx.x * TILE;

    // ---- edge meta ----
    if (t < TILE) {
        int eid = gbase + t;
        int row, col, ty; float dval = 0.f;
        if (eid >= NEFF)        { ty = 1; row = -1; col = 0; }
        else if (eid < E1N)     { ty = 0; row = E2d_idx[eid]; col = E2d_idx[E1N + eid]; }
        else if (eid < E1N + NN){ ty = 1; int jj = eid - E1N; row = jj; col = jj + NN; }
        else { ty = 2; int g2 = eid - E1N - NN;
               row = Edist_idx[g2]; col = Edist_idx[E2N + g2]; dval = Edist_val[g2]; }
        int rs = (row < 0) ? 0 : row;
        float prx = Z[rs * 3], pry = Z[rs * 3 + 1], prz = Z[rs * 3 + 2];
        float pcx, pcy, pcz;
        if (col < NN) { pcx = Z[col * 3]; pcy = Z[col * 3 + 1]; pcz = Z[col * 3 + 2]; }
        else { int c = col - NN; pcx = Z3d[c * 3]; pcy = Z3d[c * 3 + 1]; pcz = Z3d[c * 3 + 2]; }
        float dx = prx - pcx, dy = pry - pcy, dz = prz - pcz;
        float dist = sqrtf(dx * dx + dy * dy + dz * dz + 1e-8f);
        float inv = 1.0f / dist;
        s_row[t] = row; s_col[t] = col; s_type[t] = ty;
        s_vcol[t] = (col < NN) ? col : -1;
        s_unit[t][0] = dx * inv; s_unit[t][1] = dy * inv; s_unit[t][2] = dz * inv;
        s_dist[t] = dist; s_dval[t] = dval;
    }
    for (int i = t; i < 384; i += 256) ((float*)s_bt)[i] = b_type[i];
    __syncthreads();

    // ---- stage A1 = [nodes_bf16[col] | pre], rbfd = bf16(rbf(dist)) ----
    for (int i = t; i < TILE * 16; i += 256) {     // left 128: 16B vector gather
        int e = i >> 4, q = i & 15;
        *reinterpret_cast<uint4*>(&A1[e][q * 8]) =
            *reinterpret_cast<const uint4*>(nodesb + (size_t)s_col[e] * 128 + q * 8);
    }
    for (int i = t; i < TILE * 128; i += 256) {    // right 128: pre = [feat64 | rbf(dval)64]
        int k = i >> 6, e = i & 63;
        int ty = s_type[e];
        float v = 0.f;
        if (ty == 0) { if (k < 64) v = E2d_feat[(size_t)k * E1N + gbase + e]; }
        else if (ty == 2) { if (k >= 64) v = rbf_val(s_dval[e], k - 64); }
        A1[e][128 + k] = f2bf(v);
    }
    for (int i = t; i < TILE * 64; i += 256) {
        int k = i >> 6, e = i & 63;
        rbfd[e][k] = f2bf(rbf_val(s_dist[e], k));
    }
    __syncthreads();

    const int w  = t >> 6, lane = t & 63;
    const int mh = w >> 1, nh = w & 1;           // wave: 32 edges x 64 channels
    const int lr = lane >> 4, lc = lane & 15;
    const int ar0 = mh * 32 + lc;

    // ---- phi1: (64 x 256) @ W1c^T -> silu -> hid bf16 ----
    f32x4 acc[2][4];
#pragma unroll
    for (int mt = 0; mt < 2; ++mt)
#pragma unroll
        for (int nt = 0; nt < 4; ++nt) acc[mt][nt] = (f32x4){0.f, 0.f, 0.f, 0.f};
#pragma unroll
    for (int ks = 0; ks < 8; ++ks) {
        bf16x8 a0 = *reinterpret_cast<const bf16x8*>(&A1[ar0][ks * 32 + lr * 8]);
        bf16x8 a1 = *reinterpret_cast<const bf16x8*>(&A1[ar0 + 16][ks * 32 + lr * 8]);
#pragma unroll
        for (int nt = 0; nt < 4; ++nt) {
            int n = nh * 64 + nt * 16 + lc;
            bf16x8 b = *reinterpret_cast<const bf16x8*>(W1c + (size_t)n * 256 + ks * 32 + lr * 8);
            acc[0][nt] = __builtin_amdgcn_mfma_f32_16x16x32_bf16(a0, b, acc[0][nt], 0, 0, 0);
            acc[1][nt] = __builtin_amdgcn_mfma_f32_16x16x32_bf16(a1, b, acc[1][nt], 0, 0, 0);
        }
    }
    __syncthreads();   // A1 reads complete; reuse as hid
#pragma unroll
    for (int mt = 0; mt < 2; ++mt)
#pragma unroll
        for (int nt = 0; nt < 4; ++nt)
#pragma unroll
            for (int r = 0; r < 4; ++r) {
                int e  = mh * 32 + mt * 16 + lr * 4 + r;
                int ch = nh * 64 + nt * 16 + lc;
                float x = acc[mt][nt][r] + s_bt[s_type[e]][ch];
                hid[e][ch] = f2bf(x / (1.0f + __expf(-x)));
            }
    __syncthreads();

    // ---- phi2 + wd in 3 channel-chunks of 128; m = phi*wd; scatter ----
    f32x4 vgr[2][4];
#pragma unroll
    for (int c = 0; c < 3; ++c) {
        f32x4 p[2][4], g[2][4];
#pragma unroll
        for (int mt = 0; mt < 2; ++mt)
#pragma unroll
            for (int nt = 0; nt < 4; ++nt) {
                p[mt][nt] = (f32x4){0.f, 0.f, 0.f, 0.f};
                g[mt][nt] = (f32x4){0.f, 0.f, 0.f, 0.f};
            }
#pragma unroll
        for (int ks = 0; ks < 4; ++ks) {
            bf16x8 a0 = *reinterpret_cast<const bf16x8*>(&hid[ar0][ks * 32 + lr * 8]);
            bf16x8 a1 = *reinterpret_cast<const bf16x8*>(&hid[ar0 + 16][ks * 32 + lr * 8]);
#pragma unroll
            for (int nt = 0; nt < 4; ++nt) {
                int n = c * 128 + nh * 64 + nt * 16 + lc;
                bf16x8 b = *reinterpret_cast<const bf16x8*>(W2b + (size_t)n * 128 + ks * 32 + lr * 8);
                p[0][nt] = __builtin_amdgcn_mfma_f32_16x16x32_bf16(a0, b, p[0][nt], 0, 0, 0);
                p[1][nt] = __builtin_amdgcn_mfma_f32_16x16x32_bf16(a1, b, p[1][nt], 0, 0, 0);
            }
        }
#pragma unroll
        for (int ks = 0; ks < 2; ++ks) {
            bf16x8 a0 = *reinterpret_cast<const bf16x8*>(&rbfd[ar0][ks * 32 + lr * 8]);
            bf16x8 a1 = *reinterpret_cast<const bf16x8*>(&rbfd[ar0 + 16][ks * 32 + lr * 8]);
#pragma unroll
            for (int nt = 0; nt < 4; ++nt) {
                int n = c * 128 + nh * 64 + nt * 16 + lc;
                bf16x8 b = *reinterpret_cast<const bf16x8*>(Wmb + (size_t)n * 64 + ks * 32 + lr * 8);
                g[0][nt] = __builtin_amdgcn_mfma_f32_16x16x32_bf16(a0, b, g[0][nt], 0, 0, 0);
                g[1][nt] = __builtin_amdgcn_mfma_f32_16x16x32_bf16(a1, b, g[1][nt], 0, 0, 0);
            }
        }
#pragma unroll
        for (int mt = 0; mt < 2; ++mt)
#pragma unroll
            for (int nt = 0; nt < 4; ++nt) {
                int d  = nh * 64 + nt * 16 + lc;
                float b2 = b_phi2[c * 128 + d];
                float bm = b_msg[c * 128 + d];
#pragma unroll
                for (int r = 0; r < 4; ++r) {
                    int e = mh * 32 + mt * 16 + lr * 4 + r;
                    float m = (p[mt][nt][r] + b2) * (g[mt][nt][r] + bm);
                    if (c == 0) {
                        int row = s_row[e];
                        if (row >= 0) unsafeAtomicAdd(&Hout[(size_t)row * 128 + d], m);
                    } else if (c == 1) {
                        vgr[mt][nt][r] = m;
                    } else {
                        int row = s_row[e];
                        if (row >= 0) {
                            float vgv = vgr[mt][nt][r];
                            int vc = s_vcol[e];
                            float vx = 0.f, vy = 0.f, vz = 0.f;
                            if (vc >= 0) {
                                const float* vp = V + ((size_t)vc * 128 + d) * 3;
                                vx = vp[0]; vy = vp[1]; vz = vp[2];
                            }
                            float* vo = Vout + ((size_t)row * 128 + d) * 3;
                            unsafeAtomicAdd(vo + 0, vx * vgv + s_unit[e][0] * m);
                            unsafeAtomicAdd(vo + 1, vy * vgv + s_unit[e][1] * m);
                            unsafeAtomicAdd(vo + 2, vz * vgv + s_unit[e][2] * m);
                        }
                    }
                }
            }
    }
}

extern "C" void kernel_launch(void* const* d_in, const int* in_sizes, int n_in,
                              void* d_out, int out_size, void* d_ws, size_t ws_size,
                              hipStream_t stream) {
    const float* H         = (const float*)d_in[0];
    const float* V         = (const float*)d_in[1];
    const float* Z         = (const float*)d_in[2];
    const float* H2d       = (const float*)d_in[4];
    const int*   E2d_idx   = (const int*)d_in[6];
    const float* E2d_feat  = (const float*)d_in[7];
    const float* Z3d       = (const float*)d_in[8];
    const int*   Edist_idx = (const int*)d_in[10];
    const float* Edist_val = (const float*)d_in[11];
    const float* virt      = (const float*)d_in[12];
    const float* et        = (const float*)d_in[13];
    const float* W_rbf     = (const float*)d_in[14];
    const float* W_e2d     = (const float*)d_in[15];
    const float* W_i       = (const float*)d_in[16];
    const float* W_phi1    = (const float*)d_in[17];
    const float* b_phi1    = (const float*)d_in[18];
    const float* W_phi2    = (const float*)d_in[19];
    const float* b_phi2    = (const float*)d_in[20];
    const float* W_msg     = (const float*)d_in[21];
    const float* b_msg     = (const float*)d_in[22];

    ushort* nodesb = (ushort*)d_ws;              // 40000*128 bf16 = 10.24 MB
    ushort* W1c    = nodesb + 5120000;           // (128,256)
    ushort* W2b    = W1c + 32768;                // (384,128)
    ushort* Wmb    = W2b + 49152;                // (384,64)
    float*  b_type = (float*)(Wmb + 24576);      // (3,128)

    float* Hout = (float*)d_out;
    float* Vout = Hout + (size_t)NN * 128;

    hipMemsetAsync(d_out, 0, (size_t)out_size * sizeof(float), stream);
    prep_kernel<<<(32768 + 49152 + 24576 + 384 + 255) / 256, 256, 0, stream>>>(
        W_phi1, b_phi1, W_e2d, W_rbf, W_phi2, W_msg, et, W1c, W2b, Wmb, b_type);
    nodes_kernel<<<(2 * NN) / 16, 256, 0, stream>>>(H, H2d, virt, W_i, nodesb);
    edge_kernel<<<(NEFF + TILE - 1) / TILE, 256, 0, stream>>>(
        nodesb, V, Z, Z3d, E2d_idx, E2d_feat, Edist_idx, Edist_val,
        W1c, W2b, Wmb, b_type, b_phi2, b_msg, Hout, Vout);
}

// Round 3
// 1061.976 us; speedup vs baseline: 1.4475x; 1.0070x over previous
//
#include <hip/hip_runtime.h>
#include <hip/hip_bf16.h>

#define NN   20000
#define E1N  100000
#define E2N  100000
#define NEFF 220000                     /* effective edges (skip row>=n half of E3d) */
#define TILE 64
#define NBLK ((NEFF + TILE - 1) / TILE) /* 3438 */

typedef short  bf16x8 __attribute__((ext_vector_type(8)));
typedef float  f32x4  __attribute__((ext_vector_type(4)));

__device__ __forceinline__ float4 ld4(const float* p) {
    return *reinterpret_cast<const float4*>(p);
}
__device__ __forceinline__ ushort f2bf(float x) {
    __hip_bfloat16 h = __float2bfloat16(x);
    return *reinterpret_cast<ushort*>(&h);
}

// rbf_expand: centers = linspace(0,6,64) -> step 6/63; width = 6/64
__device__ __forceinline__ float rbf_val(float d, int k) {
    const float step = 0.09523809523809523f;   // 6/63
    const float inv2w2 = 56.88888888888889f;   // 1/(2*(6/64)^2)
    float c = (float)k * step;
    float t = d - c;
    float x = d * (1.0f / 6.0f);
    x = fminf(fmaxf(x, 0.0f), 1.0f);
    float env = 0.5f * (__cosf(3.14159265358979f * x) + 1.0f);
    return __expf(-t * t * inv2w2) * env;
}

__device__ __forceinline__ int edge_row(int eid, const int* __restrict__ E2d_idx,
                                        const int* __restrict__ Edist_idx) {
    if (eid < E1N) return E2d_idx[eid];
    if (eid < E1N + NN) return eid - E1N;
    return Edist_idx[eid - E1N - NN];
}

// ---------------- sort pipeline ----------------
__global__ __launch_bounds__(256) void hist_kernel(
    const int* __restrict__ E2d_idx, const int* __restrict__ Edist_idx,
    int* __restrict__ hist) {
    int g = blockIdx.x * 256 + threadIdx.x;
    if (g < NEFF) atomicAdd(&hist[edge_row(g, E2d_idx, Edist_idx)], 1);
}

__global__ __launch_bounds__(1024) void scan_kernel(
    const int* __restrict__ hist, int* __restrict__ start, int* __restrict__ cursor) {
    __shared__ int buf[1024];
    __shared__ int carry;
    const int t = threadIdx.x;
    if (t == 0) carry = 0;
    __syncthreads();
    for (int chunk = 0; chunk < 20; ++chunk) {
        int idx = chunk * 1024 + t;
        int v = (idx < NN) ? hist[idx] : 0;
        buf[t] = v;
        __syncthreads();
        for (int off = 1; off < 1024; off <<= 1) {
            int x = (t >= off) ? buf[t - off] : 0;
            __syncthreads();
            buf[t] += x;
            __syncthreads();
        }
        int excl  = buf[t] - v;
        int cbase = carry;
        int tot   = buf[1023];
        if (idx <= NN) {
            start[idx] = cbase + excl;
            if (idx < NN) cursor[idx] = cbase + excl;
        }
        __syncthreads();
        if (t == 0) carry = cbase + tot;
        __syncthreads();
    }
}

__global__ __launch_bounds__(256) void scatter_kernel(
    const int* __restrict__ E2d_idx, const int* __restrict__ Edist_idx,
    int* __restrict__ cursor, int* __restrict__ order) {
    int g = blockIdx.x * 256 + threadIdx.x;
    if (g < NEFF) {
        int r = edge_row(g, E2d_idx, Edist_idx);
        int pos = atomicAdd(&cursor[r], 1);
        order[pos] = g;
    }
}

// ---------------- prep: folded/bf16 weights ----------------
__global__ __launch_bounds__(256) void prep_kernel(
    const float* __restrict__ W_phi1, const float* __restrict__ b_phi1,
    const float* __restrict__ W_e2d, const float* __restrict__ W_rbf,
    const float* __restrict__ W_phi2, const float* __restrict__ W_msg,
    const float* __restrict__ et,
    ushort* __restrict__ W1c, ushort* __restrict__ W2b,
    ushort* __restrict__ Wmb, float* __restrict__ b_type) {
    int g = blockIdx.x * 256 + threadIdx.x;
    if (g < 32768) {
        int n = g >> 8, k = g & 255;
        float v;
        if (k < 128) v = W_phi1[n * 288 + k];
        else {
            int kk = k - 128;
            const float* Wsel = (kk < 64) ? W_e2d : W_rbf;  // both (128,64)
            int j = kk & 63;
            float s = 0.f;
            for (int a = 0; a < 128; ++a) s += W_phi1[n * 288 + 128 + a] * Wsel[a * 64 + j];
            v = s;
        }
        W1c[n * 256 + k] = f2bf(v);
    } else if (g < 32768 + 49152) {
        int q = g - 32768; W2b[q] = f2bf(W_phi2[q]);
    } else if (g < 32768 + 49152 + 24576) {
        int q = g - 81920; Wmb[q] = f2bf(W_msg[q]);
    } else if (g < 32768 + 49152 + 24576 + 384) {
        int q = g - 106496; int ty = q >> 7, n = q & 127;
        float s = b_phi1[n];
        for (int a = 0; a < 32; ++a) s += W_phi1[n * 288 + 256 + a] * et[ty * 32 + a];
        b_type[q] = s;
    }
}

// ---------------- nodes = concat([H||H2d, H||virt]) @ W_i.T (bf16 out) ----------------
__global__ __launch_bounds__(256) void nodes_kernel(
    const float* __restrict__ H, const float* __restrict__ H2d,
    const float* __restrict__ virt, const float* __restrict__ Wi,
    ushort* __restrict__ nodesb) {
    __shared__ float x[16][256];
    const int t = threadIdx.x;
    const int rbase = blockIdx.x * 16;

    for (int i = t; i < 16 * 64; i += 256) {
        int r = i >> 6, q = i & 63;
        int row = rbase + r;
        float4 v;
        if (row < NN) {
            v = (q < 32) ? ld4(H + row * 128 + q * 4) : ld4(H2d + row * 128 + (q - 32) * 4);
        } else {
            int rr = row - NN;
            v = (q < 32) ? ld4(H + rr * 128 + q * 4) : ld4(virt + (q - 32) * 4);
        }
        *reinterpret_cast<float4*>(&x[r][q * 4]) = v;
    }
    __syncthreads();

    const int j = t & 127;
    const int rg = t >> 7;
    float acc[8] = {0.f, 0.f, 0.f, 0.f, 0.f, 0.f, 0.f, 0.f};
    for (int k4 = 0; k4 < 64; ++k4) {
        float4 w = ld4(Wi + j * 256 + k4 * 4);
#pragma unroll
        for (int r = 0; r < 8; ++r) {
            float4 xv = *reinterpret_cast<const float4*>(&x[rg * 8 + r][k4 * 4]);
            acc[r] += w.x * xv.x + w.y * xv.y + w.z * xv.z + w.w * xv.w;
        }
    }
#pragma unroll
    for (int r = 0; r < 8; ++r)
        nodesb[(rbase + rg * 8 + r) * 128 + j] = f2bf(acc[r]);
}

// ---------------- fused MFMA edge pipeline ----------------
// MODE 0: atomic scatter to Hout/Vout (fallback). MODE 1: sorted order + payload store.
template <int MODE>
__global__ __launch_bounds__(256, 3) void edge_kernel(
    const ushort* __restrict__ nodesb, const float* __restrict__ V,
    const float* __restrict__ Z, const float* __restrict__ Z3d,
    const int* __restrict__ E2d_idx, const float* __restrict__ E2d_feat,
    const int* __restrict__ Edist_idx, const float* __restrict__ Edist_val,
    const ushort* __restrict__ W1c, const ushort* __restrict__ W2b,
    const ushort* __restrict__ Wmb, const float* __restrict__ b_type,
    const float* __restrict__ b_phi2, const float* __restrict__ b_msg,
    const int* __restrict__ order, float* __restrict__ payload,
    float* __restrict__ Hout, float* __restrict__ Vout) {

    __shared__ ushort A1[TILE][264];    // phi1 input K=256 (+8 pad); aliased as hid[64][136]
    __shared__ ushort rbfd[TILE][72];   // rbf(dist) K=64 (+8 pad)
    __shared__ float  s_bt[3][128];
    __shared__ int    s_row[TILE], s_col[TILE], s_vcol[TILE], s_type[TILE], s_e2d[TILE];
    __shared__ float  s_unit[TILE][3], s_dist[TILE], s_dval[TILE];

    ushort (*hid)[136] = reinterpret_cast<ushort(*)[136]>(&A1[0][0]);

    const int t = threadIdx.x;
    const int gbase = blockIdx.x * TILE;

    // ---- edge meta ----
    if (t < TILE) {
        int p = gbase + t;
        int eid;
        if (MODE == 1) eid = (p < NEFF) ? order[p] : -1;
        else           eid = (p < NEFF) ? p : -1;
        int row, col, ty, e2 = 0; float dval = 0.f;
        if (eid < 0)             { ty = 1; row = -1; col = 0; }
        else if (eid < E1N)      { ty = 0; row = E2d_idx[eid]; col = E2d_idx[E1N + eid]; e2 = eid; }
        else if (eid < E1N + NN) { ty = 1; int jj = eid - E1N; row = jj; col = jj + NN; }
        else { ty = 2; int g2 = eid - E1N - NN;
               row = Edist_idx[g2]; col = Edist_idx[E2N + g2]; dval = Edist_val[g2]; }
        int rs = (row < 0) ? 0 : row;
        float prx = Z[rs * 3], pry = Z[rs * 3 + 1], prz = Z[rs * 3 + 2];
        float pcx, pcy, pcz;
        if (col < NN) { pcx = Z[col * 3]; pcy = Z[col * 3 + 1]; pcz = Z[col * 3 + 2]; }
        else { int c = col - NN; pcx = Z3d[c * 3]; pcy = Z3d[c * 3 + 1]; pcz = Z3d[c * 3 + 2]; }
        float dx = prx - pcx, dy = pry - pcy, dz = prz - pcz;
        float dist = sqrtf(dx * dx + dy * dy + dz * dz + 1e-8f);
        float inv = 1.0f / dist;
        s_row[t] = row; s_col[t] = col; s_type[t] = ty; s_e2d[t] = e2;
        s_vcol[t] = (col < NN) ? col : -1;
        s_unit[t][0] = dx * inv; s_unit[t][1] = dy * inv; s_unit[t][2] = dz * inv;
        s_dist[t] = dist; s_dval[t] = dval;
    }
    for (int i = t; i < 384; i += 256) ((float*)s_bt)[i] = b_type[i];
    __syncthreads();

    // ---- stage A1 = [nodes_bf16[col] | pre], rbfd = bf16(rbf(dist)) ----
    for (int i = t; i < TILE * 16; i += 256) {     // left 128: 16B vector gather
        int e = i >> 4, q = i & 15;
        *reinterpret_cast<uint4*>(&A1[e][q * 8]) =
            *reinterpret_cast<const uint4*>(nodesb + (size_t)s_col[e] * 128 + q * 8);
    }
    for (int i = t; i < TILE * 128; i += 256) {    // right 128: pre = [feat64 | rbf(dval)64]
        int k = i >> 6, e = i & 63;
        int ty = s_type[e];
        float v = 0.f;
        if (ty == 0) { if (k < 64) v = E2d_feat[(size_t)k * E1N + s_e2d[e]]; }
        else if (ty == 2) { if (k >= 64) v = rbf_val(s_dval[e], k - 64); }
        A1[e][128 + k] = f2bf(v);
    }
    for (int i = t; i < TILE * 64; i += 256) {
        int k = i >> 6, e = i & 63;
        rbfd[e][k] = f2bf(rbf_val(s_dist[e], k));
    }
    __syncthreads();

    const int w  = t >> 6, lane = t & 63;
    const int mh = w >> 1, nh = w & 1;           // wave: 32 edges x 64 channels
    const int lr = lane >> 4, lc = lane & 15;
    const int ar0 = mh * 32 + lc;

    // ---- phi1: (64 x 256) @ W1c^T -> silu -> hid bf16 ----
    f32x4 acc[2][4];
#pragma unroll
    for (int mt = 0; mt < 2; ++mt)
#pragma unroll
        for (int nt = 0; nt < 4; ++nt) acc[mt][nt] = (f32x4){0.f, 0.f, 0.f, 0.f};
#pragma unroll
    for (int ks = 0; ks < 8; ++ks) {
        bf16x8 a0 = *reinterpret_cast<const bf16x8*>(&A1[ar0][ks * 32 + lr * 8]);
        bf16x8 a1 = *reinterpret_cast<const bf16x8*>(&A1[ar0 + 16][ks * 32 + lr * 8]);
#pragma unroll
        for (int nt = 0; nt < 4; ++nt) {
            int n = nh * 64 + nt * 16 + lc;
            bf16x8 b = *reinterpret_cast<const bf16x8*>(W1c + (size_t)n * 256 + ks * 32 + lr * 8);
            acc[0][nt] = __builtin_amdgcn_mfma_f32_16x16x32_bf16(a0, b, acc[0][nt], 0, 0, 0);
            acc[1][nt] = __builtin_amdgcn_mfma_f32_16x16x32_bf16(a1, b, acc[1][nt], 0, 0, 0);
        }
    }
    __syncthreads();   // A1 reads complete; reuse as hid
#pragma unroll
    for (int mt = 0; mt < 2; ++mt)
#pragma unroll
        for (int nt = 0; nt < 4; ++nt)
#pragma unroll
            for (int r = 0; r < 4; ++r) {
                int e  = mh * 32 + mt * 16 + lr * 4 + r;
                int ch = nh * 64 + nt * 16 + lc;
                float x = acc[mt][nt][r] + s_bt[s_type[e]][ch];
                hid[e][ch] = f2bf(x / (1.0f + __expf(-x)));
            }
    __syncthreads();

    // ---- phi2 + wd in 3 channel-chunks of 128; m = phi*wd; emit ----
    f32x4 vgr[2][4];
#pragma unroll
    for (int c = 0; c < 3; ++c) {
        f32x4 p[2][4], g[2][4];
#pragma unroll
        for (int mt = 0; mt < 2; ++mt)
#pragma unroll
            for (int nt = 0; nt < 4; ++nt) {
                p[mt][nt] = (f32x4){0.f, 0.f, 0.f, 0.f};
                g[mt][nt] = (f32x4){0.f, 0.f, 0.f, 0.f};
            }
#pragma unroll
        for (int ks = 0; ks < 4; ++ks) {
            bf16x8 a0 = *reinterpret_cast<const bf16x8*>(&hid[ar0][ks * 32 + lr * 8]);
            bf16x8 a1 = *reinterpret_cast<const bf16x8*>(&hid[ar0 + 16][ks * 32 + lr * 8]);
#pragma unroll
            for (int nt = 0; nt < 4; ++nt) {
                int n = c * 128 + nh * 64 + nt * 16 + lc;
                bf16x8 b = *reinterpret_cast<const bf16x8*>(W2b + (size_t)n * 128 + ks * 32 + lr * 8);
                p[0][nt] = __builtin_amdgcn_mfma_f32_16x16x32_bf16(a0, b, p[0][nt], 0, 0, 0);
                p[1][nt] = __builtin_amdgcn_mfma_f32_16x16x32_bf16(a1, b, p[1][nt], 0, 0, 0);
            }
        }
#pragma unroll
        for (int ks = 0; ks < 2; ++ks) {
            bf16x8 a0 = *reinterpret_cast<const bf16x8*>(&rbfd[ar0][ks * 32 + lr * 8]);
            bf16x8 a1 = *reinterpret_cast<const bf16x8*>(&rbfd[ar0 + 16][ks * 32 + lr * 8]);
#pragma unroll
            for (int nt = 0; nt < 4; ++nt) {
                int n = c * 128 + nh * 64 + nt * 16 + lc;
                bf16x8 b = *reinterpret_cast<const bf16x8*>(Wmb + (size_t)n * 64 + ks * 32 + lr * 8);
                g[0][nt] = __builtin_amdgcn_mfma_f32_16x16x32_bf16(a0, b, g[0][nt], 0, 0, 0);
                g[1][nt] = __builtin_amdgcn_mfma_f32_16x16x32_bf16(a1, b, g[1][nt], 0, 0, 0);
            }
        }
#pragma unroll
        for (int mt = 0; mt < 2; ++mt)
#pragma unroll
            for (int nt = 0; nt < 4; ++nt) {
                int d  = nh * 64 + nt * 16 + lc;
                float b2 = b_phi2[c * 128 + d];
                float bm = b_msg[c * 128 + d];
#pragma unroll
                for (int r = 0; r < 4; ++r) {
                    int e = mh * 32 + mt * 16 + lr * 4 + r;
                    float m = (p[mt][nt][r] + b2) * (g[mt][nt][r] + bm);
                    if (c == 0) {
                        int row = s_row[e];
                        if (row >= 0) {
                            if (MODE == 0) unsafeAtomicAdd(&Hout[(size_t)row * 128 + d], m);
                            else payload[(size_t)(gbase + e) * 512 + d] = m;
                        }
                    } else if (c == 1) {
                        vgr[mt][nt][r] = m;
                    } else {
                        int row = s_row[e];
                        if (row >= 0) {
                            float vgv = vgr[mt][nt][r];
                            int vc = s_vcol[e];
                            float vx = 0.f, vy = 0.f, vz = 0.f;
                            if (vc >= 0) {
                                const float* vp = V + ((size_t)vc * 128 + d) * 3;
                                vx = vp[0]; vy = vp[1]; vz = vp[2];
                            }
                            float ax = vx * vgv + s_unit[e][0] * m;
                            float ay = vy * vgv + s_unit[e][1] * m;
                            float az = vz * vgv + s_unit[e][2] * m;
                            if (MODE == 0) {
                                float* vo = Vout + ((size_t)row * 128 + d) * 3;
                                unsafeAtomicAdd(vo + 0, ax);
                                unsafeAtomicAdd(vo + 1, ay);
                                unsafeAtomicAdd(vo + 2, az);
                            } else {
                                float* pp = payload + (size_t)(gbase + e) * 512 + 128 + d * 3;
                                pp[0] = ax; pp[1] = ay; pp[2] = az;
                            }
                        }
                    }
                }
            }
    }
}

// ---------------- reduce: one block per row, stream sorted payload ----------------
__global__ __launch_bounds__(256) void reduce_kernel(
    const float* __restrict__ payload, const int* __restrict__ start,
    float* __restrict__ Hout, float* __restrict__ Vout) {
    const int r = blockIdx.x;
    const int t = threadIdx.x;
    const int s0 = start[r], s1 = start[r + 1];
    float a0 = 0.f, a1 = 0.f;
    for (int i = s0; i < s1; ++i) {
        const float* p = payload + (size_t)i * 512;
        a0 += p[t];
        a1 += p[t + 256];
    }
    a0 = fminf(fmaxf(a0, -100.f), 100.f);
    a1 = fminf(fmaxf(a1, -100.f), 100.f);
    if (t < 128) Hout[(size_t)r * 128 + t] = a0;
    else         Vout[(size_t)r * 384 + (t - 128)] = a0;
    Vout[(size_t)r * 384 + (t + 128)] = a1;
}

extern "C" void kernel_launch(void* const* d_in, const int* in_sizes, int n_in,
                              void* d_out, int out_size, void* d_ws, size_t ws_size,
                              hipStream_t stream) {
    const float* H         = (const float*)d_in[0];
    const float* V         = (const float*)d_in[1];
    const float* Z         = (const float*)d_in[2];
    const float* H2d       = (const float*)d_in[4];
    const int*   E2d_idx   = (const int*)d_in[6];
    const float* E2d_feat  = (const float*)d_in[7];
    const float* Z3d       = (const float*)d_in[8];
    const int*   Edist_idx = (const int*)d_in[10];
    const float* Edist_val = (const float*)d_in[11];
    const float* virt      = (const float*)d_in[12];
    const float* et        = (const float*)d_in[13];
    const float* W_rbf     = (const float*)d_in[14];
    const float* W_e2d     = (const float*)d_in[15];
    const float* W_i       = (const float*)d_in[16];
    const float* W_phi1    = (const float*)d_in[17];
    const float* b_phi1    = (const float*)d_in[18];
    const float* W_phi2    = (const float*)d_in[19];
    const float* b_phi2    = (const float*)d_in[20];
    const float* W_msg     = (const float*)d_in[21];
    const float* b_msg     = (const float*)d_in[22];

    ushort* nodesb = (ushort*)d_ws;              // 40000*128 bf16 = 10.24 MB
    ushort* W1c    = nodesb + 5120000;           // (128,256)
    ushort* W2b    = W1c + 32768;                // (384,128)
    ushort* Wmb    = W2b + 49152;                // (384,64)
    float*  b_type = (float*)(Wmb + 24576);      // (3,128)
    int*    hist   = (int*)(b_type + 384);       // NN
    int*    cursor = hist + NN;                  // NN
    int*    start  = cursor + NN;                // NN+1
    int*    order  = start + (NN + 1);           // NBLK*TILE

    size_t used = (size_t)((char*)(order + NBLK * TILE) - (char*)d_ws);
    size_t poff = (used + 255) & ~(size_t)255;
    float* payload = (float*)((char*)d_ws + poff);
    size_t needed = poff + (size_t)NBLK * TILE * 512 * sizeof(float);  // ~463 MB
    const bool big = (ws_size >= needed);

    float* Hout = (float*)d_out;
    float* Vout = Hout + (size_t)NN * 128;

    prep_kernel<<<(32768 + 49152 + 24576 + 384 + 255) / 256, 256, 0, stream>>>(
        W_phi1, b_phi1, W_e2d, W_rbf, W_phi2, W_msg, et, W1c, W2b, Wmb, b_type);
    nodes_kernel<<<(2 * NN) / 16, 256, 0, stream>>>(H, H2d, virt, W_i, nodesb);

    if (big) {
        hipMemsetAsync(hist, 0, NN * sizeof(int), stream);
        hist_kernel<<<(NEFF + 255) / 256, 256, 0, stream>>>(E2d_idx, Edist_idx, hist);
        scan_kernel<<<1, 1024, 0, stream>>>(hist, start, cursor);
        scatter_kernel<<<(NEFF + 255) / 256, 256, 0, stream>>>(E2d_idx, Edist_idx, cursor, order);
        edge_kernel<1><<<NBLK, 256, 0, stream>>>(
            nodesb, V, Z, Z3d, E2d_idx, E2d_feat, Edist_idx, Edist_val,
            W1c, W2b, Wmb, b_type, b_phi2, b_msg, order, payload, Hout, Vout);
        reduce_kernel<<<NN, 256, 0, stream>>>(payload, start, Hout, Vout);
    } else {
        hipMemsetAsync(d_out, 0, (size_t)out_size * sizeof(float), stream);
        edge_kernel<0><<<NBLK, 256, 0, stream>>>(
            nodesb, V, Z, Z3d, E2d_idx, E2d_feat, Edist_idx, Edist_val,
            W1c, W2b, Wmb, b_type, b_phi2, b_msg, order, payload, Hout, Vout);
    }
}

// Round 4
// 770.864 us; speedup vs baseline: 1.9941x; 1.3776x over previous
//
#include <hip/hip_runtime.h>
#include <hip/hip_bf16.h>

#define NN   20000
#define E1N  100000
#define E2N  100000
#define NEFF 220000                     /* effective edges (skip row>=n half of E3d) */
#define TILE 64
#define NBLK ((NEFF + TILE - 1) / TILE) /* 3438 */
#define RBF_STEP   0.09523809523809523f /* 6/63 */
#define RBF_INV2W2 56.88888888888889f   /* 1/(2*(6/64)^2) */

typedef short  bf16x8 __attribute__((ext_vector_type(8)));
typedef float  f32x4  __attribute__((ext_vector_type(4)));

__device__ __forceinline__ float4 ld4(const float* p) {
    return *reinterpret_cast<const float4*>(p);
}
__device__ __forceinline__ ushort f2bf(float x) {
    __hip_bfloat16 h = __float2bfloat16(x);
    return *reinterpret_cast<ushort*>(&h);
}
__device__ __forceinline__ float env_of(float d) {
    float x = fminf(fmaxf(d * (1.0f / 6.0f), 0.0f), 1.0f);
    return 0.5f * (__cosf(3.14159265358979f * x) + 1.0f);
}

__device__ __forceinline__ int edge_row(int eid, const int* __restrict__ E2d_idx,
                                        const int* __restrict__ Edist_idx) {
    if (eid < E1N) return E2d_idx[eid];
    if (eid < E1N + NN) return eid - E1N;
    return Edist_idx[eid - E1N - NN];
}

// ---------------- sort pipeline ----------------
__global__ __launch_bounds__(256) void hist_kernel(
    const int* __restrict__ E2d_idx, const int* __restrict__ Edist_idx,
    int* __restrict__ hist) {
    int g = blockIdx.x * 256 + threadIdx.x;
    if (g < NEFF) atomicAdd(&hist[edge_row(g, E2d_idx, Edist_idx)], 1);
}

__global__ __launch_bounds__(1024) void scan_kernel(
    const int* __restrict__ hist, int* __restrict__ start, int* __restrict__ cursor) {
    __shared__ int buf[1024];
    __shared__ int carry;
    const int t = threadIdx.x;
    if (t == 0) carry = 0;
    __syncthreads();
    for (int chunk = 0; chunk < 20; ++chunk) {
        int idx = chunk * 1024 + t;
        int v = (idx < NN) ? hist[idx] : 0;
        buf[t] = v;
        __syncthreads();
        for (int off = 1; off < 1024; off <<= 1) {
            int x = (t >= off) ? buf[t - off] : 0;
            __syncthreads();
            buf[t] += x;
            __syncthreads();
        }
        int excl  = buf[t] - v;
        int cbase = carry;
        int tot   = buf[1023];
        if (idx <= NN) {
            start[idx] = cbase + excl;
            if (idx < NN) cursor[idx] = cbase + excl;
        }
        __syncthreads();
        if (t == 0) carry = cbase + tot;
        __syncthreads();
    }
}

__global__ __launch_bounds__(256) void scatter_kernel(
    const int* __restrict__ E2d_idx, const int* __restrict__ Edist_idx,
    int* __restrict__ cursor, int* __restrict__ order) {
    int g = blockIdx.x * 256 + threadIdx.x;
    if (g < NEFF) {
        int r = edge_row(g, E2d_idx, Edist_idx);
        int pos = atomicAdd(&cursor[r], 1);
        order[pos] = g;
    }
}

__global__ __launch_bounds__(64) void chunkrow_kernel(
    const int* __restrict__ order, const int* __restrict__ E2d_idx,
    const int* __restrict__ Edist_idx, int cap, int nch, int* __restrict__ chunk_r0) {
    int i = threadIdx.x;
    if (i < nch) {
        int p = i * cap;
        if (p >= NEFF) p = NEFF - 1;
        chunk_r0[i] = edge_row(order[p], E2d_idx, Edist_idx);
    }
}

// ---------------- prep: folded/bf16 weights ----------------
__global__ __launch_bounds__(256) void prep_kernel(
    const float* __restrict__ W_phi1, const float* __restrict__ b_phi1,
    const float* __restrict__ W_e2d, const float* __restrict__ W_rbf,
    const float* __restrict__ W_phi2, const float* __restrict__ W_msg,
    const float* __restrict__ et,
    ushort* __restrict__ W1c, ushort* __restrict__ W2b,
    ushort* __restrict__ Wmb, float* __restrict__ b_type) {
    int g = blockIdx.x * 256 + threadIdx.x;
    if (g < 32768) {
        int n = g >> 8, k = g & 255;
        float v;
        if (k < 128) v = W_phi1[n * 288 + k];
        else {
            int kk = k - 128;
            const float* Wsel = (kk < 64) ? W_e2d : W_rbf;  // both (128,64)
            int j = kk & 63;
            float s = 0.f;
            for (int a = 0; a < 128; ++a) s += W_phi1[n * 288 + 128 + a] * Wsel[a * 64 + j];
            v = s;
        }
        W1c[n * 256 + k] = f2bf(v);
    } else if (g < 32768 + 49152) {
        int q = g - 32768; W2b[q] = f2bf(W_phi2[q]);
    } else if (g < 32768 + 49152 + 24576) {
        int q = g - 81920; Wmb[q] = f2bf(W_msg[q]);
    } else if (g < 32768 + 49152 + 24576 + 384) {
        int q = g - 106496; int ty = q >> 7, n = q & 127;
        float s = b_phi1[n];
        for (int a = 0; a < 32; ++a) s += W_phi1[n * 288 + 256 + a] * et[ty * 32 + a];
        b_type[q] = s;
    }
}

// ---------------- featT: transpose E2d_feat (64,E1N) -> bf16 (E1N,64) ----------------
__global__ __launch_bounds__(256) void featT_kernel(
    const float* __restrict__ feat, ushort* __restrict__ featTb) {
    __shared__ float tile[64][65];
    const int t = threadIdx.x;
    const int cbase = blockIdx.x * 64;
    for (int i = t; i < 64 * 64; i += 256) {
        int k = i >> 6, e = i & 63;
        tile[k][e] = (cbase + e < E1N) ? feat[(size_t)k * E1N + cbase + e] : 0.f;
    }
    __syncthreads();
    for (int i = t; i < 64 * 64; i += 256) {
        int e = i >> 6, k = i & 63;
        if (cbase + e < E1N) featTb[(size_t)(cbase + e) * 64 + k] = f2bf(tile[k][e]);
    }
}

// ---------------- nodes = concat([H||H2d, H||virt]) @ W_i.T (bf16 out) ----------------
__global__ __launch_bounds__(256) void nodes_kernel(
    const float* __restrict__ H, const float* __restrict__ H2d,
    const float* __restrict__ virt, const float* __restrict__ Wi,
    ushort* __restrict__ nodesb) {
    __shared__ float x[16][256];
    const int t = threadIdx.x;
    const int rbase = blockIdx.x * 16;

    for (int i = t; i < 16 * 64; i += 256) {
        int r = i >> 6, q = i & 63;
        int row = rbase + r;
        float4 v;
        if (row < NN) {
            v = (q < 32) ? ld4(H + row * 128 + q * 4) : ld4(H2d + row * 128 + (q - 32) * 4);
        } else {
            int rr = row - NN;
            v = (q < 32) ? ld4(H + rr * 128 + q * 4) : ld4(virt + (q - 32) * 4);
        }
        *reinterpret_cast<float4*>(&x[r][q * 4]) = v;
    }
    __syncthreads();

    const int j = t & 127;
    const int rg = t >> 7;
    float acc[8] = {0.f, 0.f, 0.f, 0.f, 0.f, 0.f, 0.f, 0.f};
    for (int k4 = 0; k4 < 64; ++k4) {
        float4 w = ld4(Wi + j * 256 + k4 * 4);
#pragma unroll
        for (int r = 0; r < 8; ++r) {
            float4 xv = *reinterpret_cast<const float4*>(&x[rg * 8 + r][k4 * 4]);
            acc[r] += w.x * xv.x + w.y * xv.y + w.z * xv.z + w.w * xv.w;
        }
    }
#pragma unroll
    for (int r = 0; r < 8; ++r)
        nodesb[(rbase + rg * 8 + r) * 128 + j] = f2bf(acc[r]);
}

// ---------------- fused MFMA edge pipeline ----------------
// MODE 0: atomic scatter (fallback). MODE 1: sorted chunk + payload store.
template <int MODE>
__global__ __launch_bounds__(256, 3) void edge_kernel(
    const ushort* __restrict__ nodesb, const float* __restrict__ V,
    const float* __restrict__ Z, const float* __restrict__ Z3d,
    const int* __restrict__ E2d_idx, const float* __restrict__ E2d_feat,
    const ushort* __restrict__ featTb,
    const int* __restrict__ Edist_idx, const float* __restrict__ Edist_val,
    const ushort* __restrict__ W1c, const ushort* __restrict__ W2b,
    const ushort* __restrict__ Wmb, const float* __restrict__ b_type,
    const float* __restrict__ b_phi2, const float* __restrict__ b_msg,
    const int* __restrict__ order, int p0, float* __restrict__ payload,
    float* __restrict__ Hout, float* __restrict__ Vout) {

    __shared__ ushort A1[TILE][264];    // phi1 input K=256 (+8 pad); aliased as hid[64][136]
    __shared__ ushort rbfd[TILE][72];   // rbf(dist) K=64 (+8 pad)
    __shared__ float  s_bt[3][128];
    __shared__ int    s_row[TILE], s_col[TILE], s_vcol[TILE], s_type[TILE], s_e2d[TILE];
    __shared__ float  s_unit[TILE][3], s_dist[TILE], s_dval[TILE];
    __shared__ float  s_env[TILE], s_env2[TILE];

    ushort (*hid)[136] = reinterpret_cast<ushort(*)[136]>(&A1[0][0]);

    const int t = threadIdx.x;
    const int gbase = blockIdx.x * TILE;   // chunk-local base

    // ---- edge meta ----
    if (t < TILE) {
        int gpos = (MODE == 1) ? (p0 + gbase + t) : (gbase + t);
        int eid = (gpos < NEFF) ? ((MODE == 1) ? order[gpos] : gpos) : -1;
        int row, col, ty, e2 = 0; float dval = 0.f;
        if (eid < 0)             { ty = 1; row = -1; col = 0; }
        else if (eid < E1N)      { ty = 0; row = E2d_idx[eid]; col = E2d_idx[E1N + eid]; e2 = eid; }
        else if (eid < E1N + NN) { ty = 1; int jj = eid - E1N; row = jj; col = jj + NN; }
        else { ty = 2; int g2 = eid - E1N - NN;
               row = Edist_idx[g2]; col = Edist_idx[E2N + g2]; dval = Edist_val[g2]; }
        int rs = (row < 0) ? 0 : row;
        float prx = Z[rs * 3], pry = Z[rs * 3 + 1], prz = Z[rs * 3 + 2];
        float pcx, pcy, pcz;
        if (col < NN) { pcx = Z[col * 3]; pcy = Z[col * 3 + 1]; pcz = Z[col * 3 + 2]; }
        else { int c = col - NN; pcx = Z3d[c * 3]; pcy = Z3d[c * 3 + 1]; pcz = Z3d[c * 3 + 2]; }
        float dx = prx - pcx, dy = pry - pcy, dz = prz - pcz;
        float dist = sqrtf(dx * dx + dy * dy + dz * dz + 1e-8f);
        float inv = 1.0f / dist;
        s_row[t] = row; s_col[t] = col; s_type[t] = ty; s_e2d[t] = e2;
        s_vcol[t] = (col < NN) ? col : -1;
        s_unit[t][0] = dx * inv; s_unit[t][1] = dy * inv; s_unit[t][2] = dz * inv;
        s_dist[t] = dist; s_dval[t] = dval;
        s_env[t] = env_of(dist); s_env2[t] = env_of(dval);
    }
    for (int i = t; i < 384; i += 256) ((float*)s_bt)[i] = b_type[i];
    __syncthreads();

    // ---- stage A1 = [nodes_bf16[col] | pre], rbfd = bf16(rbf(dist)) ----
    for (int i = t; i < TILE * 16; i += 256) {     // left 128: 16B vector gather
        int e = i >> 4, q = i & 15;
        *reinterpret_cast<uint4*>(&A1[e][q * 8]) =
            *reinterpret_cast<const uint4*>(nodesb + (size_t)s_col[e] * 128 + q * 8);
    }
    if (MODE == 1) {
        for (int i = t; i < TILE * 128; i += 256) {  // right 128: [featT | rbf(dval)]
            int e = i >> 7, k = i & 127;
            int ty = s_type[e];
            ushort v = 0;
            if (ty == 0) { if (k < 64) v = featTb[(size_t)s_e2d[e] * 64 + k]; }
            else if (ty == 2) {
                if (k >= 64) {
                    float dd = s_dval[e] - (float)(k - 64) * RBF_STEP;
                    v = f2bf(__expf(-dd * dd * RBF_INV2W2) * s_env2[e]);
                }
            }
            A1[e][128 + k] = v;
        }
    } else {
        for (int i = t; i < TILE * 128; i += 256) {
            int k = i >> 6, e = i & 63;
            int ty = s_type[e];
            float v = 0.f;
            if (ty == 0) { if (k < 64) v = E2d_feat[(size_t)k * E1N + s_e2d[e]]; }
            else if (ty == 2) {
                if (k >= 64) {
                    float dd = s_dval[e] - (float)(k - 64) * RBF_STEP;
                    v = __expf(-dd * dd * RBF_INV2W2) * s_env2[e];
                }
            }
            A1[e][128 + k] = f2bf(v);
        }
    }
    for (int i = t; i < TILE * 64; i += 256) {
        int k = i >> 6, e = i & 63;
        float dd = s_dist[e] - (float)k * RBF_STEP;
        rbfd[e][k] = f2bf(__expf(-dd * dd * RBF_INV2W2) * s_env[e]);
    }
    __syncthreads();

    const int w  = t >> 6, lane = t & 63;
    const int mh = w >> 1, nh = w & 1;           // wave: 32 edges x 64 channels
    const int lr = lane >> 4, lc = lane & 15;
    const int ar0 = mh * 32 + lc;

    // ---- phi1: (64 x 256) @ W1c^T -> silu -> hid bf16 ----
    f32x4 acc[2][4];
#pragma unroll
    for (int mt = 0; mt < 2; ++mt)
#pragma unroll
        for (int nt = 0; nt < 4; ++nt) acc[mt][nt] = (f32x4){0.f, 0.f, 0.f, 0.f};
#pragma unroll
    for (int ks = 0; ks < 8; ++ks) {
        bf16x8 a0 = *reinterpret_cast<const bf16x8*>(&A1[ar0][ks * 32 + lr * 8]);
        bf16x8 a1 = *reinterpret_cast<const bf16x8*>(&A1[ar0 + 16][ks * 32 + lr * 8]);
#pragma unroll
        for (int nt = 0; nt < 4; ++nt) {
            int n = nh * 64 + nt * 16 + lc;
            bf16x8 b = *reinterpret_cast<const bf16x8*>(W1c + (size_t)n * 256 + ks * 32 + lr * 8);
            acc[0][nt] = __builtin_amdgcn_mfma_f32_16x16x32_bf16(a0, b, acc[0][nt], 0, 0, 0);
            acc[1][nt] = __builtin_amdgcn_mfma_f32_16x16x32_bf16(a1, b, acc[1][nt], 0, 0, 0);
        }
    }
    __syncthreads();   // A1 reads complete; reuse as hid
#pragma unroll
    for (int mt = 0; mt < 2; ++mt)
#pragma unroll
        for (int nt = 0; nt < 4; ++nt)
#pragma unroll
            for (int r = 0; r < 4; ++r) {
                int e  = mh * 32 + mt * 16 + lr * 4 + r;
                int ch = nh * 64 + nt * 16 + lc;
                float x = acc[mt][nt][r] + s_bt[s_type[e]][ch];
                hid[e][ch] = f2bf(x / (1.0f + __expf(-x)));
            }
    __syncthreads();

    // ---- phi2 + wd in 3 channel-chunks of 128; m = phi*wd; emit ----
    f32x4 vgr[2][4];
#pragma unroll
    for (int c = 0; c < 3; ++c) {
        f32x4 p[2][4], g[2][4];
#pragma unroll
        for (int mt = 0; mt < 2; ++mt)
#pragma unroll
            for (int nt = 0; nt < 4; ++nt) {
                p[mt][nt] = (f32x4){0.f, 0.f, 0.f, 0.f};
                g[mt][nt] = (f32x4){0.f, 0.f, 0.f, 0.f};
            }
#pragma unroll
        for (int ks = 0; ks < 4; ++ks) {
            bf16x8 a0 = *reinterpret_cast<const bf16x8*>(&hid[ar0][ks * 32 + lr * 8]);
            bf16x8 a1 = *reinterpret_cast<const bf16x8*>(&hid[ar0 + 16][ks * 32 + lr * 8]);
#pragma unroll
            for (int nt = 0; nt < 4; ++nt) {
                int n = c * 128 + nh * 64 + nt * 16 + lc;
                bf16x8 b = *reinterpret_cast<const bf16x8*>(W2b + (size_t)n * 128 + ks * 32 + lr * 8);
                p[0][nt] = __builtin_amdgcn_mfma_f32_16x16x32_bf16(a0, b, p[0][nt], 0, 0, 0);
                p[1][nt] = __builtin_amdgcn_mfma_f32_16x16x32_bf16(a1, b, p[1][nt], 0, 0, 0);
            }
        }
#pragma unroll
        for (int ks = 0; ks < 2; ++ks) {
            bf16x8 a0 = *reinterpret_cast<const bf16x8*>(&rbfd[ar0][ks * 32 + lr * 8]);
            bf16x8 a1 = *reinterpret_cast<const bf16x8*>(&rbfd[ar0 + 16][ks * 32 + lr * 8]);
#pragma unroll
            for (int nt = 0; nt < 4; ++nt) {
                int n = c * 128 + nh * 64 + nt * 16 + lc;
                bf16x8 b = *reinterpret_cast<const bf16x8*>(Wmb + (size_t)n * 64 + ks * 32 + lr * 8);
                g[0][nt] = __builtin_amdgcn_mfma_f32_16x16x32_bf16(a0, b, g[0][nt], 0, 0, 0);
                g[1][nt] = __builtin_amdgcn_mfma_f32_16x16x32_bf16(a1, b, g[1][nt], 0, 0, 0);
            }
        }
#pragma unroll
        for (int mt = 0; mt < 2; ++mt)
#pragma unroll
            for (int nt = 0; nt < 4; ++nt) {
                int d  = nh * 64 + nt * 16 + lc;
                float b2 = b_phi2[c * 128 + d];
                float bm = b_msg[c * 128 + d];
#pragma unroll
                for (int r = 0; r < 4; ++r) {
                    int e = mh * 32 + mt * 16 + lr * 4 + r;
                    float m = (p[mt][nt][r] + b2) * (g[mt][nt][r] + bm);
                    if (c == 0) {
                        int row = s_row[e];
                        if (row >= 0) {
                            if (MODE == 0) unsafeAtomicAdd(&Hout[(size_t)row * 128 + d], m);
                            else payload[(size_t)(gbase + e) * 512 + d] = m;
                        }
                    } else if (c == 1) {
                        vgr[mt][nt][r] = m;
                    } else {
                        int row = s_row[e];
                        if (row >= 0) {
                            float vgv = vgr[mt][nt][r];
                            int vc = s_vcol[e];
                            float vx = 0.f, vy = 0.f, vz = 0.f;
                            if (vc >= 0) {
                                const float* vp = V + ((size_t)vc * 128 + d) * 3;
                                vx = vp[0]; vy = vp[1]; vz = vp[2];
                            }
                            float ax = vx * vgv + s_unit[e][0] * m;
                            float ay = vy * vgv + s_unit[e][1] * m;
                            float az = vz * vgv + s_unit[e][2] * m;
                            if (MODE == 0) {
                                float* vo = Vout + ((size_t)row * 128 + d) * 3;
                                unsafeAtomicAdd(vo + 0, ax);
                                unsafeAtomicAdd(vo + 1, ay);
                                unsafeAtomicAdd(vo + 2, az);
                            } else {
                                float* pp = payload + (size_t)(gbase + e) * 512 + 128 + d * 3;
                                pp[0] = ax; pp[1] = ay; pp[2] = az;
                            }
                        }
                    }
                }
            }
    }
}

// ---------------- reduce: accumulate chunk payload into output ----------------
__global__ __launch_bounds__(256) void reduce_kernel(
    const float* __restrict__ payload, const int* __restrict__ start,
    const int* __restrict__ chunk_r0, int ci, int p0, int p1,
    float* __restrict__ Hout, float* __restrict__ Vout) {
    const int t = threadIdx.x;
    const int rbase = chunk_r0[ci] + blockIdx.x * 8;
    for (int nr = 0; nr < 8; ++nr) {
        int r = rbase + nr;
        if (r >= NN) return;
        int s0 = start[r], s1 = start[r + 1];
        if (s0 >= p1) return;            // rows are sorted; nothing further in chunk
        int a = (s0 > p0) ? s0 : p0;
        int b = (s1 < p1) ? s1 : p1;
        if (a >= b) continue;            // empty row
        float a0 = 0.f, a1 = 0.f;
        for (int i = a; i < b; ++i) {
            const float* p = payload + (size_t)(i - p0) * 512;
            a0 += p[t];
            a1 += p[t + 256];
        }
        float* ptr0 = (t < 128) ? &Hout[(size_t)r * 128 + t]
                                : &Vout[(size_t)r * 384 + (t - 128)];
        float* ptr1 = &Vout[(size_t)r * 384 + (t + 128)];
        float o0 = *ptr0 + a0;
        float o1 = *ptr1 + a1;
        if (s1 <= p1) {                  // row complete -> final clip
            o0 = fminf(fmaxf(o0, -100.f), 100.f);
            o1 = fminf(fmaxf(o1, -100.f), 100.f);
        }
        *ptr0 = o0;
        *ptr1 = o1;
    }
}

extern "C" void kernel_launch(void* const* d_in, const int* in_sizes, int n_in,
                              void* d_out, int out_size, void* d_ws, size_t ws_size,
                              hipStream_t stream) {
    const float* H         = (const float*)d_in[0];
    const float* V         = (const float*)d_in[1];
    const float* Z         = (const float*)d_in[2];
    const float* H2d       = (const float*)d_in[4];
    const int*   E2d_idx   = (const int*)d_in[6];
    const float* E2d_feat  = (const float*)d_in[7];
    const float* Z3d       = (const float*)d_in[8];
    const int*   Edist_idx = (const int*)d_in[10];
    const float* Edist_val = (const float*)d_in[11];
    const float* virt      = (const float*)d_in[12];
    const float* et        = (const float*)d_in[13];
    const float* W_rbf     = (const float*)d_in[14];
    const float* W_e2d     = (const float*)d_in[15];
    const float* W_i       = (const float*)d_in[16];
    const float* W_phi1    = (const float*)d_in[17];
    const float* b_phi1    = (const float*)d_in[18];
    const float* W_phi2    = (const float*)d_in[19];
    const float* b_phi2    = (const float*)d_in[20];
    const float* W_msg     = (const float*)d_in[21];
    const float* b_msg     = (const float*)d_in[22];

    ushort* nodesb  = (ushort*)d_ws;                 // 40000*128 bf16
    ushort* W1c     = nodesb + 5120000;              // (128,256)
    ushort* W2b     = W1c + 32768;                   // (384,128)
    ushort* Wmb     = W2b + 49152;                   // (384,64)
    float*  b_type  = (float*)(Wmb + 24576);         // (3,128)
    ushort* featTb  = (ushort*)(b_type + 384);       // (E1N,64) bf16 = 12.8 MB
    int*    hist    = (int*)(featTb + (size_t)E1N * 64);
    int*    cursor  = hist + NN;
    int*    start   = cursor + NN;                   // NN+1
    int*    order   = start + NN + 1;                // NBLK*TILE
    int*    chunk_r0= order + NBLK * TILE;           // 64

    size_t fixed = (size_t)((char*)(chunk_r0 + 64) - (char*)d_ws);
    size_t poff  = (fixed + 255) & ~(size_t)255;
    float* payload = (float*)((char*)d_ws + poff);
    size_t avail = (ws_size > poff) ? (ws_size - poff) : 0;
    long long cap_ll = (long long)(avail / 2048) / TILE * TILE;   // edges per chunk
    int cap = (cap_ll > (long long)NBLK * TILE) ? NBLK * TILE : (int)cap_ll;
    const bool big = (cap >= 4096);

    float* Hout = (float*)d_out;
    float* Vout = Hout + (size_t)NN * 128;

    hipMemsetAsync(d_out, 0, (size_t)out_size * sizeof(float), stream);
    prep_kernel<<<(32768 + 49152 + 24576 + 384 + 255) / 256, 256, 0, stream>>>(
        W_phi1, b_phi1, W_e2d, W_rbf, W_phi2, W_msg, et, W1c, W2b, Wmb, b_type);
    nodes_kernel<<<(2 * NN) / 16, 256, 0, stream>>>(H, H2d, virt, W_i, nodesb);

    if (big) {
        hipMemsetAsync(hist, 0, NN * sizeof(int), stream);
        featT_kernel<<<(E1N + 63) / 64, 256, 0, stream>>>(E2d_feat, featTb);
        hist_kernel<<<(NEFF + 255) / 256, 256, 0, stream>>>(E2d_idx, Edist_idx, hist);
        scan_kernel<<<1, 1024, 0, stream>>>(hist, start, cursor);
        scatter_kernel<<<(NEFF + 255) / 256, 256, 0, stream>>>(E2d_idx, Edist_idx, cursor, order);
        int bpc = cap / TILE;
        int nch = (NBLK + bpc - 1) / bpc;
        chunkrow_kernel<<<1, 64, 0, stream>>>(order, E2d_idx, Edist_idx, cap, nch, chunk_r0);
        int rbound = (NN < cap + 1) ? NN : (cap + 1);
        int rgrid  = (rbound + 7) / 8;
        for (int ci = 0; ci < nch; ++ci) {
            int b0 = ci * bpc;
            int nb = ((NBLK - b0) < bpc) ? (NBLK - b0) : bpc;
            int p0 = b0 * TILE;
            int p1 = p0 + nb * TILE; if (p1 > NEFF) p1 = NEFF;
            edge_kernel<1><<<nb, 256, 0, stream>>>(
                nodesb, V, Z, Z3d, E2d_idx, E2d_feat, featTb, Edist_idx, Edist_val,
                W1c, W2b, Wmb, b_type, b_phi2, b_msg, order, p0, payload, Hout, Vout);
            reduce_kernel<<<rgrid, 256, 0, stream>>>(payload, start, chunk_r0, ci, p0, p1,
                                                     Hout, Vout);
        }
    } else {
        edge_kernel<0><<<NBLK, 256, 0, stream>>>(
            nodesb, V, Z, Z3d, E2d_idx, E2d_feat, featTb, Edist_idx, Edist_val,
            W1c, W2b, Wmb, b_type, b_phi2, b_msg, order, 0, payload, Hout, Vout);
    }
}

// Round 5
// 631.477 us; speedup vs baseline: 2.4343x; 1.2207x over previous
//
#include <hip/hip_runtime.h>
#include <hip/hip_bf16.h>

#define NN   20000
#define E1N  100000
#define E2N  100000
#define NEFF 220000                     /* effective edges (skip row>=n half of E3d) */
#define TILE 64
#define NBLK ((NEFF + TILE - 1) / TILE) /* 3438 */
#define RBF_STEP   0.09523809523809523f /* 6/63 */
#define RBF_INV2W2 56.88888888888889f   /* 1/(2*(6/64)^2) */

typedef short  bf16x8 __attribute__((ext_vector_type(8)));
typedef float  f32x4  __attribute__((ext_vector_type(4)));

__device__ __forceinline__ float4 ld4(const float* p) {
    return *reinterpret_cast<const float4*>(p);
}
__device__ __forceinline__ ushort f2bf(float x) {
    __hip_bfloat16 h = __float2bfloat16(x);
    return *reinterpret_cast<ushort*>(&h);
}
__device__ __forceinline__ float env_of(float d) {
    float x = fminf(fmaxf(d * (1.0f / 6.0f), 0.0f), 1.0f);
    return 0.5f * (__cosf(3.14159265358979f * x) + 1.0f);
}

__device__ __forceinline__ int edge_row(int eid, const int* __restrict__ E2d_idx,
                                        const int* __restrict__ Edist_idx) {
    if (eid < E1N) return E2d_idx[eid];
    if (eid < E1N + NN) return eid - E1N;
    return Edist_idx[eid - E1N - NN];
}

// ---------------- sort pipeline ----------------
__global__ __launch_bounds__(256) void hist_kernel(
    const int* __restrict__ E2d_idx, const int* __restrict__ Edist_idx,
    int* __restrict__ hist) {
    int g = blockIdx.x * 256 + threadIdx.x;
    if (g < NEFF) atomicAdd(&hist[edge_row(g, E2d_idx, Edist_idx)], 1);
}

__global__ __launch_bounds__(1024) void scan_kernel(
    const int* __restrict__ hist, int* __restrict__ start, int* __restrict__ cursor) {
    __shared__ int buf[1024];
    __shared__ int carry;
    const int t = threadIdx.x;
    if (t == 0) carry = 0;
    __syncthreads();
    for (int chunk = 0; chunk < 20; ++chunk) {
        int idx = chunk * 1024 + t;
        int v = (idx < NN) ? hist[idx] : 0;
        buf[t] = v;
        __syncthreads();
        for (int off = 1; off < 1024; off <<= 1) {
            int x = (t >= off) ? buf[t - off] : 0;
            __syncthreads();
            buf[t] += x;
            __syncthreads();
        }
        int excl  = buf[t] - v;
        int cbase = carry;
        int tot   = buf[1023];
        if (idx <= NN) {
            start[idx] = cbase + excl;
            if (idx < NN) cursor[idx] = cbase + excl;
        }
        __syncthreads();
        if (t == 0) carry = cbase + tot;
        __syncthreads();
    }
}

__global__ __launch_bounds__(256) void scatter_kernel(
    const int* __restrict__ E2d_idx, const int* __restrict__ Edist_idx,
    int* __restrict__ cursor, int* __restrict__ order) {
    int g = blockIdx.x * 256 + threadIdx.x;
    if (g < NEFF) {
        int r = edge_row(g, E2d_idx, Edist_idx);
        int pos = atomicAdd(&cursor[r], 1);
        order[pos] = g;
    }
}

__global__ __launch_bounds__(64) void chunkrow_kernel(
    const int* __restrict__ order, const int* __restrict__ E2d_idx,
    const int* __restrict__ Edist_idx, int cap, int nch, int* __restrict__ chunk_r0) {
    int i = threadIdx.x;
    if (i < nch) {
        int p = i * cap;
        if (p >= NEFF) p = NEFF - 1;
        chunk_r0[i] = edge_row(order[p], E2d_idx, Edist_idx);
    }
}

// ---------------- prep: folded/bf16 weights ----------------
__global__ __launch_bounds__(256) void prep_kernel(
    const float* __restrict__ W_phi1, const float* __restrict__ b_phi1,
    const float* __restrict__ W_e2d, const float* __restrict__ W_rbf,
    const float* __restrict__ W_phi2, const float* __restrict__ W_msg,
    const float* __restrict__ et,
    ushort* __restrict__ W1c, ushort* __restrict__ W2b,
    ushort* __restrict__ Wmb, float* __restrict__ b_type) {
    int g = blockIdx.x * 256 + threadIdx.x;
    if (g < 32768) {
        int n = g >> 8, k = g & 255;
        float v;
        if (k < 128) v = W_phi1[n * 288 + k];
        else {
            int kk = k - 128;
            const float* Wsel = (kk < 64) ? W_e2d : W_rbf;  // both (128,64)
            int j = kk & 63;
            float s = 0.f;
            for (int a = 0; a < 128; ++a) s += W_phi1[n * 288 + 128 + a] * Wsel[a * 64 + j];
            v = s;
        }
        W1c[n * 256 + k] = f2bf(v);
    } else if (g < 32768 + 49152) {
        int q = g - 32768; W2b[q] = f2bf(W_phi2[q]);
    } else if (g < 32768 + 49152 + 24576) {
        int q = g - 81920; Wmb[q] = f2bf(W_msg[q]);
    } else if (g < 32768 + 49152 + 24576 + 384) {
        int q = g - 106496; int ty = q >> 7, n = q & 127;
        float s = b_phi1[n];
        for (int a = 0; a < 32; ++a) s += W_phi1[n * 288 + 256 + a] * et[ty * 32 + a];
        b_type[q] = s;
    }
}

// ---------------- featT: transpose E2d_feat (64,E1N) -> bf16 (E1N,64) ----------------
__global__ __launch_bounds__(256) void featT_kernel(
    const float* __restrict__ feat, ushort* __restrict__ featTb) {
    __shared__ float tile[64][65];
    const int t = threadIdx.x;
    const int cbase = blockIdx.x * 64;
    for (int i = t; i < 64 * 64; i += 256) {
        int k = i >> 6, e = i & 63;
        tile[k][e] = (cbase + e < E1N) ? feat[(size_t)k * E1N + cbase + e] : 0.f;
    }
    __syncthreads();
    for (int i = t; i < 64 * 64; i += 256) {
        int e = i >> 6, k = i & 63;
        if (cbase + e < E1N) featTb[(size_t)(cbase + e) * 64 + k] = f2bf(tile[k][e]);
    }
}

// ---------------- nodes = concat([H||H2d, H||virt]) @ W_i.T (bf16 out) ----------------
__global__ __launch_bounds__(256) void nodes_kernel(
    const float* __restrict__ H, const float* __restrict__ H2d,
    const float* __restrict__ virt, const float* __restrict__ Wi,
    ushort* __restrict__ nodesb) {
    __shared__ float x[16][256];
    const int t = threadIdx.x;
    const int rbase = blockIdx.x * 16;

    for (int i = t; i < 16 * 64; i += 256) {
        int r = i >> 6, q = i & 63;
        int row = rbase + r;
        float4 v;
        if (row < NN) {
            v = (q < 32) ? ld4(H + row * 128 + q * 4) : ld4(H2d + row * 128 + (q - 32) * 4);
        } else {
            int rr = row - NN;
            v = (q < 32) ? ld4(H + rr * 128 + q * 4) : ld4(virt + (q - 32) * 4);
        }
        *reinterpret_cast<float4*>(&x[r][q * 4]) = v;
    }
    __syncthreads();

    const int j = t & 127;
    const int rg = t >> 7;
    float acc[8] = {0.f, 0.f, 0.f, 0.f, 0.f, 0.f, 0.f, 0.f};
    for (int k4 = 0; k4 < 64; ++k4) {
        float4 w = ld4(Wi + j * 256 + k4 * 4);
#pragma unroll
        for (int r = 0; r < 8; ++r) {
            float4 xv = *reinterpret_cast<const float4*>(&x[rg * 8 + r][k4 * 4]);
            acc[r] += w.x * xv.x + w.y * xv.y + w.z * xv.z + w.w * xv.w;
        }
    }
#pragma unroll
    for (int r = 0; r < 8; ++r)
        nodesb[(rbase + rg * 8 + r) * 128 + j] = f2bf(acc[r]);
}

// ---------------- fused MFMA edge pipeline ----------------
// MODE 0: atomic scatter (fallback). MODE 1: sorted chunk + slim payload store
// (smsg/vg/rg -> payloadM[e][384]; unit+vcol -> payloadU[e]; V-gather deferred to reduce).
template <int MODE>
__global__ __launch_bounds__(256, 4) void edge_kernel(
    const ushort* __restrict__ nodesb, const float* __restrict__ V,
    const float* __restrict__ Z, const float* __restrict__ Z3d,
    const int* __restrict__ E2d_idx, const float* __restrict__ E2d_feat,
    const ushort* __restrict__ featTb,
    const int* __restrict__ Edist_idx, const float* __restrict__ Edist_val,
    const ushort* __restrict__ W1c, const ushort* __restrict__ W2b,
    const ushort* __restrict__ Wmb, const float* __restrict__ b_type,
    const float* __restrict__ b_phi2, const float* __restrict__ b_msg,
    const int* __restrict__ order, int p0,
    float* __restrict__ payloadM, float4* __restrict__ payloadU,
    float* __restrict__ Hout, float* __restrict__ Vout) {

    __shared__ ushort A1[TILE][264];    // phi1 input K=256 (+8 pad); aliased as hid[64][136]
    __shared__ float  s_bt[3][128];
    __shared__ int    s_row[TILE], s_col[TILE], s_vcol[TILE], s_type[TILE], s_e2d[TILE];
    __shared__ float  s_unit[TILE][3], s_dist[TILE], s_dval[TILE];
    __shared__ float  s_env[TILE], s_env2[TILE];

    ushort (*hid)[136] = reinterpret_cast<ushort(*)[136]>(&A1[0][0]);

    const int t = threadIdx.x;
    const int gbase = blockIdx.x * TILE;   // chunk-local base

    // ---- edge meta ----
    if (t < TILE) {
        int gpos = (MODE == 1) ? (p0 + gbase + t) : (gbase + t);
        int eid = (gpos < NEFF) ? ((MODE == 1) ? order[gpos] : gpos) : -1;
        int row, col, ty, e2 = 0; float dval = 0.f;
        if (eid < 0)             { ty = 1; row = -1; col = 0; }
        else if (eid < E1N)      { ty = 0; row = E2d_idx[eid]; col = E2d_idx[E1N + eid]; e2 = eid; }
        else if (eid < E1N + NN) { ty = 1; int jj = eid - E1N; row = jj; col = jj + NN; }
        else { ty = 2; int g2 = eid - E1N - NN;
               row = Edist_idx[g2]; col = Edist_idx[E2N + g2]; dval = Edist_val[g2]; }
        int rs = (row < 0) ? 0 : row;
        float prx = Z[rs * 3], pry = Z[rs * 3 + 1], prz = Z[rs * 3 + 2];
        float pcx, pcy, pcz;
        if (col < NN) { pcx = Z[col * 3]; pcy = Z[col * 3 + 1]; pcz = Z[col * 3 + 2]; }
        else { int c = col - NN; pcx = Z3d[c * 3]; pcy = Z3d[c * 3 + 1]; pcz = Z3d[c * 3 + 2]; }
        float dx = prx - pcx, dy = pry - pcy, dz = prz - pcz;
        float dist = sqrtf(dx * dx + dy * dy + dz * dz + 1e-8f);
        float inv = 1.0f / dist;
        int vcol = (col < NN) ? col : -1;
        s_row[t] = row; s_col[t] = col; s_type[t] = ty; s_e2d[t] = e2;
        s_vcol[t] = vcol;
        s_unit[t][0] = dx * inv; s_unit[t][1] = dy * inv; s_unit[t][2] = dz * inv;
        s_dist[t] = dist; s_dval[t] = dval;
        s_env[t] = env_of(dist); s_env2[t] = env_of(dval);
        if (MODE == 1 && row >= 0)
            payloadU[gbase + t] = make_float4(dx * inv, dy * inv, dz * inv,
                                              __int_as_float(vcol));
    }
    for (int i = t; i < 384; i += 256) ((float*)s_bt)[i] = b_type[i];
    __syncthreads();

    // ---- stage A1 = [nodes_bf16[col] | pre] ----
    for (int i = t; i < TILE * 16; i += 256) {     // left 128: 16B vector gather
        int e = i >> 4, q = i & 15;
        *reinterpret_cast<uint4*>(&A1[e][q * 8]) =
            *reinterpret_cast<const uint4*>(nodesb + (size_t)s_col[e] * 128 + q * 8);
    }
    if (MODE == 1) {
        for (int i = t; i < TILE * 128; i += 256) {  // right 128: [featT | rbf(dval)]
            int e = i >> 7, k = i & 127;
            int ty = s_type[e];
            ushort v = 0;
            if (ty == 0) { if (k < 64) v = featTb[(size_t)s_e2d[e] * 64 + k]; }
            else if (ty == 2) {
                if (k >= 64) {
                    float dd = s_dval[e] - (float)(k - 64) * RBF_STEP;
                    v = f2bf(__expf(-dd * dd * RBF_INV2W2) * s_env2[e]);
                }
            }
            A1[e][128 + k] = v;
        }
    } else {
        for (int i = t; i < TILE * 128; i += 256) {
            int k = i >> 6, e = i & 63;
            int ty = s_type[e];
            float v = 0.f;
            if (ty == 0) { if (k < 64) v = E2d_feat[(size_t)k * E1N + s_e2d[e]]; }
            else if (ty == 2) {
                if (k >= 64) {
                    float dd = s_dval[e] - (float)(k - 64) * RBF_STEP;
                    v = __expf(-dd * dd * RBF_INV2W2) * s_env2[e];
                }
            }
            A1[e][128 + k] = f2bf(v);
        }
    }
    __syncthreads();

    const int w  = t >> 6, lane = t & 63;
    const int mh = w >> 1, nh = w & 1;           // wave: 32 edges x 64 channels
    const int lr = lane >> 4, lc = lane & 15;
    const int ar0 = mh * 32 + lc;

    // ---- wd A-fragments in-register: rbf(dist) for edges ar0, ar0+16 ----
    bf16x8 ra0[2], ra1[2];   // [ks]
    {
        float dA = s_dist[ar0],      eA = s_env[ar0];
        float dB = s_dist[ar0 + 16], eB = s_env[ar0 + 16];
#pragma unroll
        for (int ks = 0; ks < 2; ++ks)
#pragma unroll
            for (int j = 0; j < 8; ++j) {
                float c  = (float)(ks * 32 + lr * 8 + j) * RBF_STEP;
                float tA = dA - c, tB = dB - c;
                ra0[ks][j] = (short)f2bf(__expf(-tA * tA * RBF_INV2W2) * eA);
                ra1[ks][j] = (short)f2bf(__expf(-tB * tB * RBF_INV2W2) * eB);
            }
    }

    // ---- phi1: (64 x 256) @ W1c^T -> silu -> hid bf16 ----
    f32x4 acc[2][4];
#pragma unroll
    for (int mt = 0; mt < 2; ++mt)
#pragma unroll
        for (int nt = 0; nt < 4; ++nt) acc[mt][nt] = (f32x4){0.f, 0.f, 0.f, 0.f};
#pragma unroll
    for (int ks = 0; ks < 8; ++ks) {
        bf16x8 a0 = *reinterpret_cast<const bf16x8*>(&A1[ar0][ks * 32 + lr * 8]);
        bf16x8 a1 = *reinterpret_cast<const bf16x8*>(&A1[ar0 + 16][ks * 32 + lr * 8]);
#pragma unroll
        for (int nt = 0; nt < 4; ++nt) {
            int n = nh * 64 + nt * 16 + lc;
            bf16x8 b = *reinterpret_cast<const bf16x8*>(W1c + (size_t)n * 256 + ks * 32 + lr * 8);
            acc[0][nt] = __builtin_amdgcn_mfma_f32_16x16x32_bf16(a0, b, acc[0][nt], 0, 0, 0);
            acc[1][nt] = __builtin_amdgcn_mfma_f32_16x16x32_bf16(a1, b, acc[1][nt], 0, 0, 0);
        }
    }
    __syncthreads();   // A1 reads complete; reuse as hid
#pragma unroll
    for (int mt = 0; mt < 2; ++mt)
#pragma unroll
        for (int nt = 0; nt < 4; ++nt)
#pragma unroll
            for (int r = 0; r < 4; ++r) {
                int e  = mh * 32 + mt * 16 + lr * 4 + r;
                int ch = nh * 64 + nt * 16 + lc;
                float x = acc[mt][nt][r] + s_bt[s_type[e]][ch];
                hid[e][ch] = f2bf(x / (1.0f + __expf(-x)));
            }
    __syncthreads();

    // ---- phi2 + wd in 3 channel-chunks of 128; m = phi*wd; emit ----
    f32x4 vgr[2][4];
#pragma unroll
    for (int c = 0; c < 3; ++c) {
        f32x4 p[2][4], g[2][4];
#pragma unroll
        for (int mt = 0; mt < 2; ++mt)
#pragma unroll
            for (int nt = 0; nt < 4; ++nt) {
                p[mt][nt] = (f32x4){0.f, 0.f, 0.f, 0.f};
                g[mt][nt] = (f32x4){0.f, 0.f, 0.f, 0.f};
            }
#pragma unroll
        for (int ks = 0; ks < 4; ++ks) {
            bf16x8 a0 = *reinterpret_cast<const bf16x8*>(&hid[ar0][ks * 32 + lr * 8]);
            bf16x8 a1 = *reinterpret_cast<const bf16x8*>(&hid[ar0 + 16][ks * 32 + lr * 8]);
#pragma unroll
            for (int nt = 0; nt < 4; ++nt) {
                int n = c * 128 + nh * 64 + nt * 16 + lc;
                bf16x8 b = *reinterpret_cast<const bf16x8*>(W2b + (size_t)n * 128 + ks * 32 + lr * 8);
                p[0][nt] = __builtin_amdgcn_mfma_f32_16x16x32_bf16(a0, b, p[0][nt], 0, 0, 0);
                p[1][nt] = __builtin_amdgcn_mfma_f32_16x16x32_bf16(a1, b, p[1][nt], 0, 0, 0);
            }
        }
#pragma unroll
        for (int ks = 0; ks < 2; ++ks) {
#pragma unroll
            for (int nt = 0; nt < 4; ++nt) {
                int n = c * 128 + nh * 64 + nt * 16 + lc;
                bf16x8 b = *reinterpret_cast<const bf16x8*>(Wmb + (size_t)n * 64 + ks * 32 + lr * 8);
                g[0][nt] = __builtin_amdgcn_mfma_f32_16x16x32_bf16(ra0[ks], b, g[0][nt], 0, 0, 0);
                g[1][nt] = __builtin_amdgcn_mfma_f32_16x16x32_bf16(ra1[ks], b, g[1][nt], 0, 0, 0);
            }
        }
#pragma unroll
        for (int mt = 0; mt < 2; ++mt)
#pragma unroll
            for (int nt = 0; nt < 4; ++nt) {
                int d  = nh * 64 + nt * 16 + lc;
                float b2 = b_phi2[c * 128 + d];
                float bm = b_msg[c * 128 + d];
#pragma unroll
                for (int r = 0; r < 4; ++r) {
                    int e = mh * 32 + mt * 16 + lr * 4 + r;
                    float m = (p[mt][nt][r] + b2) * (g[mt][nt][r] + bm);
                    int row = s_row[e];
                    if (MODE == 1) {
                        if (row >= 0) payloadM[(size_t)(gbase + e) * 384 + c * 128 + d] = m;
                    } else {
                        if (c == 0) {
                            if (row >= 0) unsafeAtomicAdd(&Hout[(size_t)row * 128 + d], m);
                        } else if (c == 1) {
                            vgr[mt][nt][r] = m;
                        } else if (row >= 0) {
                            float vgv = vgr[mt][nt][r];
                            int vc = s_vcol[e];
                            float vx = 0.f, vy = 0.f, vz = 0.f;
                            if (vc >= 0) {
                                const float* vp = V + ((size_t)vc * 128 + d) * 3;
                                vx = vp[0]; vy = vp[1]; vz = vp[2];
                            }
                            float* vo = Vout + ((size_t)row * 128 + d) * 3;
                            unsafeAtomicAdd(vo + 0, vx * vgv + s_unit[e][0] * m);
                            unsafeAtomicAdd(vo + 1, vy * vgv + s_unit[e][1] * m);
                            unsafeAtomicAdd(vo + 2, vz * vgv + s_unit[e][2] * m);
                        }
                    }
                }
            }
    }
}

// ---------------- reduce: accumulate chunk payload into output (+V gather) ----------------
__global__ __launch_bounds__(256) void reduce_kernel(
    const float* __restrict__ payloadM, const float4* __restrict__ payloadU,
    const float* __restrict__ V, const int* __restrict__ start,
    const int* __restrict__ chunk_r0, int ci, int p0, int p1,
    float* __restrict__ Hout, float* __restrict__ Vout) {
    const int t = threadIdx.x;
    const int rbase = chunk_r0[ci] + blockIdx.x * 8;
    const bool hside = (t < 128);
    const int d = hside ? t : (t - 128);
    for (int nr = 0; nr < 8; ++nr) {
        int r = rbase + nr;
        if (r >= NN) return;
        int s0 = start[r], s1 = start[r + 1];
        if (s0 >= p1) return;            // rows sorted; nothing further in chunk
        int a = (s0 > p0) ? s0 : p0;
        int b = (s1 < p1) ? s1 : p1;
        if (a >= b) continue;            // row not in this chunk
        if (hside) {
            float acc = 0.f;
            for (int i = a; i < b; ++i) acc += payloadM[(size_t)(i - p0) * 384 + d];
            float* ptr = &Hout[(size_t)r * 128 + d];
            float o = *ptr + acc;
            if (s1 <= p1) o = fminf(fmaxf(o, -100.f), 100.f);
            *ptr = o;
        } else {
            float ax = 0.f, ay = 0.f, az = 0.f;
            for (int i = a; i < b; ++i) {
                const float* pm = payloadM + (size_t)(i - p0) * 384;
                float vg = pm[128 + d], rg = pm[256 + d];
                float4 u = payloadU[i - p0];
                int vc = __float_as_int(u.w);
                if (vc >= 0) {
                    const float* vp = V + (size_t)vc * 384 + d * 3;
                    ax += vg * vp[0]; ay += vg * vp[1]; az += vg * vp[2];
                }
                ax += rg * u.x; ay += rg * u.y; az += rg * u.z;
            }
            float* vo = Vout + (size_t)r * 384 + d * 3;
            float ox = vo[0] + ax, oy = vo[1] + ay, oz = vo[2] + az;
            if (s1 <= p1) {
                ox = fminf(fmaxf(ox, -100.f), 100.f);
                oy = fminf(fmaxf(oy, -100.f), 100.f);
                oz = fminf(fmaxf(oz, -100.f), 100.f);
            }
            vo[0] = ox; vo[1] = oy; vo[2] = oz;
        }
    }
}

extern "C" void kernel_launch(void* const* d_in, const int* in_sizes, int n_in,
                              void* d_out, int out_size, void* d_ws, size_t ws_size,
                              hipStream_t stream) {
    const float* H         = (const float*)d_in[0];
    const float* V         = (const float*)d_in[1];
    const float* Z         = (const float*)d_in[2];
    const float* H2d       = (const float*)d_in[4];
    const int*   E2d_idx   = (const int*)d_in[6];
    const float* E2d_feat  = (const float*)d_in[7];
    const float* Z3d       = (const float*)d_in[8];
    const int*   Edist_idx = (const int*)d_in[10];
    const float* Edist_val = (const float*)d_in[11];
    const float* virt      = (const float*)d_in[12];
    const float* et        = (const float*)d_in[13];
    const float* W_rbf     = (const float*)d_in[14];
    const float* W_e2d     = (const float*)d_in[15];
    const float* W_i       = (const float*)d_in[16];
    const float* W_phi1    = (const float*)d_in[17];
    const float* b_phi1    = (const float*)d_in[18];
    const float* W_phi2    = (const float*)d_in[19];
    const float* b_phi2    = (const float*)d_in[20];
    const float* W_msg     = (const float*)d_in[21];
    const float* b_msg     = (const float*)d_in[22];

    ushort* nodesb  = (ushort*)d_ws;                 // 40000*128 bf16
    ushort* W1c     = nodesb + 5120000;              // (128,256)
    ushort* W2b     = W1c + 32768;                   // (384,128)
    ushort* Wmb     = W2b + 49152;                   // (384,64)
    float*  b_type  = (float*)(Wmb + 24576);         // (3,128)
    ushort* featTb  = (ushort*)(b_type + 384);       // (E1N,64) bf16 = 12.8 MB
    int*    hist    = (int*)(featTb + (size_t)E1N * 64);
    int*    cursor  = hist + NN;
    int*    start   = cursor + NN;                   // NN+1
    int*    order   = start + NN + 1;                // NBLK*TILE
    int*    chunk_r0= order + NBLK * TILE;           // 64

    size_t fixed = (size_t)((char*)(chunk_r0 + 64) - (char*)d_ws);
    size_t poff  = (fixed + 255) & ~(size_t)255;
    float* payloadM = (float*)((char*)d_ws + poff);
    size_t avail = (ws_size > poff) ? (ws_size - poff) : 0;
    long long cap_ll = (long long)(avail / 1552) / TILE * TILE;   // 384 f32 + 16 B per edge
    int cap = (cap_ll > (long long)NBLK * TILE) ? NBLK * TILE : (int)cap_ll;
    const bool big = (cap >= 4096);
    float4* payloadU = (float4*)(payloadM + (size_t)cap * 384);

    float* Hout = (float*)d_out;
    float* Vout = Hout + (size_t)NN * 128;

    hipMemsetAsync(d_out, 0, (size_t)out_size * sizeof(float), stream);
    prep_kernel<<<(32768 + 49152 + 24576 + 384 + 255) / 256, 256, 0, stream>>>(
        W_phi1, b_phi1, W_e2d, W_rbf, W_phi2, W_msg, et, W1c, W2b, Wmb, b_type);
    nodes_kernel<<<(2 * NN) / 16, 256, 0, stream>>>(H, H2d, virt, W_i, nodesb);

    if (big) {
        hipMemsetAsync(hist, 0, NN * sizeof(int), stream);
        featT_kernel<<<(E1N + 63) / 64, 256, 0, stream>>>(E2d_feat, featTb);
        hist_kernel<<<(NEFF + 255) / 256, 256, 0, stream>>>(E2d_idx, Edist_idx, hist);
        scan_kernel<<<1, 1024, 0, stream>>>(hist, start, cursor);
        scatter_kernel<<<(NEFF + 255) / 256, 256, 0, stream>>>(E2d_idx, Edist_idx, cursor, order);
        int bpc = cap / TILE;
        int nch = (NBLK + bpc - 1) / bpc;
        chunkrow_kernel<<<1, 64, 0, stream>>>(order, E2d_idx, Edist_idx, cap, nch, chunk_r0);
        int rbound = (NN < cap + 1) ? NN : (cap + 1);
        int rgrid  = (rbound + 7) / 8;
        for (int ci = 0; ci < nch; ++ci) {
            int b0 = ci * bpc;
            int nb = ((NBLK - b0) < bpc) ? (NBLK - b0) : bpc;
            int p0 = b0 * TILE;
            int p1 = p0 + nb * TILE; if (p1 > NEFF) p1 = NEFF;
            edge_kernel<1><<<nb, 256, 0, stream>>>(
                nodesb, V, Z, Z3d, E2d_idx, E2d_feat, featTb, Edist_idx, Edist_val,
                W1c, W2b, Wmb, b_type, b_phi2, b_msg, order, p0, payloadM, payloadU,
                Hout, Vout);
            reduce_kernel<<<rgrid, 256, 0, stream>>>(payloadM, payloadU, V, start,
                                                     chunk_r0, ci, p0, p1, Hout, Vout);
        }
    } else {
        edge_kernel<0><<<NBLK, 256, 0, stream>>>(
            nodesb, V, Z, Z3d, E2d_idx, E2d_feat, featTb, Edist_idx, Edist_val,
            W1c, W2b, Wmb, b_type, b_phi2, b_msg, order, 0, payloadM, payloadU,
            Hout, Vout);
    }
}

// Round 6
// 627.252 us; speedup vs baseline: 2.4507x; 1.0067x over previous
//
#include <hip/hip_runtime.h>
#include <hip/hip_bf16.h>

#define NN   20000
#define E1N  100000
#define E2N  100000
#define NEFF 220000                     /* effective edges (skip row>=n half of E3d) */
#define TILE 64
#define NBLK ((NEFF + TILE - 1) / TILE) /* 3438 */
#define NPAD (NBLK * TILE)              /* 220032 */
#define RBF_STEP   0.09523809523809523f /* 6/63 */
#define RBF_INV2W2 56.88888888888889f   /* 1/(2*(6/64)^2) */

typedef short  bf16x8 __attribute__((ext_vector_type(8)));
typedef float  f32x4  __attribute__((ext_vector_type(4)));

__device__ __forceinline__ float4 ld4(const float* p) {
    return *reinterpret_cast<const float4*>(p);
}
__device__ __forceinline__ ushort f2bf(float x) {
    __hip_bfloat16 h = __float2bfloat16(x);
    return *reinterpret_cast<ushort*>(&h);
}
__device__ __forceinline__ float env_of(float d) {
    float x = fminf(fmaxf(d * (1.0f / 6.0f), 0.0f), 1.0f);
    return 0.5f * (__cosf(3.14159265358979f * x) + 1.0f);
}

__device__ __forceinline__ int edge_row(int eid, const int* __restrict__ E2d_idx,
                                        const int* __restrict__ Edist_idx) {
    if (eid < E1N) return E2d_idx[eid];
    if (eid < E1N + NN) return eid - E1N;
    return Edist_idx[eid - E1N - NN];
}

// ---------------- sort pipeline ----------------
__global__ __launch_bounds__(256) void hist_kernel(
    const int* __restrict__ E2d_idx, const int* __restrict__ Edist_idx,
    int* __restrict__ hist) {
    int g = blockIdx.x * 256 + threadIdx.x;
    if (g < NEFF) atomicAdd(&hist[edge_row(g, E2d_idx, Edist_idx)], 1);
}

__global__ __launch_bounds__(1024) void scan_kernel(
    const int* __restrict__ hist, int* __restrict__ start, int* __restrict__ cursor) {
    __shared__ int buf[1024];
    __shared__ int carry;
    const int t = threadIdx.x;
    if (t == 0) carry = 0;
    __syncthreads();
    for (int chunk = 0; chunk < 20; ++chunk) {
        int idx = chunk * 1024 + t;
        int v = (idx < NN) ? hist[idx] : 0;
        buf[t] = v;
        __syncthreads();
        for (int off = 1; off < 1024; off <<= 1) {
            int x = (t >= off) ? buf[t - off] : 0;
            __syncthreads();
            buf[t] += x;
            __syncthreads();
        }
        int excl  = buf[t] - v;
        int cbase = carry;
        int tot   = buf[1023];
        if (idx <= NN) {
            start[idx] = cbase + excl;
            if (idx < NN) cursor[idx] = cbase + excl;
        }
        __syncthreads();
        if (t == 0) carry = cbase + tot;
        __syncthreads();
    }
}

__global__ __launch_bounds__(256) void scatter_kernel(
    const int* __restrict__ E2d_idx, const int* __restrict__ Edist_idx,
    int* __restrict__ cursor, int* __restrict__ order) {
    int g = blockIdx.x * 256 + threadIdx.x;
    if (g < NEFF) {
        int r = edge_row(g, E2d_idx, Edist_idx);
        int pos = atomicAdd(&cursor[r], 1);
        order[pos] = g;
    }
}

__global__ __launch_bounds__(64) void chunkrow_kernel(
    const int* __restrict__ order, const int* __restrict__ E2d_idx,
    const int* __restrict__ Edist_idx, int cap, int nch, int* __restrict__ chunk_r0) {
    int i = threadIdx.x;
    if (i < nch) {
        int p = i * cap;
        if (p >= NEFF) p = NEFF - 1;
        chunk_r0[i] = edge_row(order[p], E2d_idx, Edist_idx);
    }
}

// ---------------- meta: per-sorted-edge precompute (removes random-gather chain
// from the hot edge kernel; 220k threads pipeline the Z/idx latencies via TLP) ----
__global__ __launch_bounds__(256) void meta_kernel(
    const int* __restrict__ order, const int* __restrict__ E2d_idx,
    const int* __restrict__ Edist_idx, const float* __restrict__ Edist_val,
    const float* __restrict__ Z, const float* __restrict__ Z3d,
    int4* __restrict__ metaI, float4* __restrict__ metaF,
    float4* __restrict__ payloadU) {
    int g = blockIdx.x * 256 + threadIdx.x;
    if (g >= NPAD) return;
    int eid = (g < NEFF) ? order[g] : -1;
    int row, col, ty, e2 = 0; float dval = 0.f;
    if (eid < 0)             { ty = 1; row = -1; col = 0; }
    else if (eid < E1N)      { ty = 0; row = E2d_idx[eid]; col = E2d_idx[E1N + eid]; e2 = eid; }
    else if (eid < E1N + NN) { ty = 1; int jj = eid - E1N; row = jj; col = jj + NN; }
    else { ty = 2; int g2 = eid - E1N - NN;
           row = Edist_idx[g2]; col = Edist_idx[E2N + g2]; dval = Edist_val[g2]; }
    int rs = (row < 0) ? 0 : row;
    float prx = Z[rs * 3], pry = Z[rs * 3 + 1], prz = Z[rs * 3 + 2];
    float pcx, pcy, pcz;
    if (col < NN) { pcx = Z[col * 3]; pcy = Z[col * 3 + 1]; pcz = Z[col * 3 + 2]; }
    else { int c = col - NN; pcx = Z3d[c * 3]; pcy = Z3d[c * 3 + 1]; pcz = Z3d[c * 3 + 2]; }
    float dx = prx - pcx, dy = pry - pcy, dz = prz - pcz;
    float dist = sqrtf(dx * dx + dy * dy + dz * dz + 1e-8f);
    float inv = 1.0f / dist;
    int vcol = (col < NN) ? col : -1;
    metaI[g] = make_int4(col, row, ty, e2);
    metaF[g] = make_float4(dist, dval, env_of(dist), env_of(dval));
    if (row >= 0)
        payloadU[g] = make_float4(dx * inv, dy * inv, dz * inv, __int_as_float(vcol));
}

// ---------------- prep: folded/bf16 weights ----------------
__global__ __launch_bounds__(256) void prep_kernel(
    const float* __restrict__ W_phi1, const float* __restrict__ b_phi1,
    const float* __restrict__ W_e2d, const float* __restrict__ W_rbf,
    const float* __restrict__ W_phi2, const float* __restrict__ W_msg,
    const float* __restrict__ et,
    ushort* __restrict__ W1c, ushort* __restrict__ W2b,
    ushort* __restrict__ Wmb, float* __restrict__ b_type) {
    int g = blockIdx.x * 256 + threadIdx.x;
    if (g < 32768) {
        int n = g >> 8, k = g & 255;
        float v;
        if (k < 128) v = W_phi1[n * 288 + k];
        else {
            int kk = k - 128;
            const float* Wsel = (kk < 64) ? W_e2d : W_rbf;  // both (128,64)
            int j = kk & 63;
            float s = 0.f;
            for (int a = 0; a < 128; ++a) s += W_phi1[n * 288 + 128 + a] * Wsel[a * 64 + j];
            v = s;
        }
        W1c[n * 256 + k] = f2bf(v);
    } else if (g < 32768 + 49152) {
        int q = g - 32768; W2b[q] = f2bf(W_phi2[q]);
    } else if (g < 32768 + 49152 + 24576) {
        int q = g - 81920; Wmb[q] = f2bf(W_msg[q]);
    } else if (g < 32768 + 49152 + 24576 + 384) {
        int q = g - 106496; int ty = q >> 7, n = q & 127;
        float s = b_phi1[n];
        for (int a = 0; a < 32; ++a) s += W_phi1[n * 288 + 256 + a] * et[ty * 32 + a];
        b_type[q] = s;
    }
}

// ---------------- featT: transpose E2d_feat (64,E1N) -> bf16 (E1N,64) ----------------
__global__ __launch_bounds__(256) void featT_kernel(
    const float* __restrict__ feat, ushort* __restrict__ featTb) {
    __shared__ float tile[64][65];
    const int t = threadIdx.x;
    const int cbase = blockIdx.x * 64;
    for (int i = t; i < 64 * 64; i += 256) {
        int k = i >> 6, e = i & 63;
        tile[k][e] = (cbase + e < E1N) ? feat[(size_t)k * E1N + cbase + e] : 0.f;
    }
    __syncthreads();
    for (int i = t; i < 64 * 64; i += 256) {
        int e = i >> 6, k = i & 63;
        if (cbase + e < E1N) featTb[(size_t)(cbase + e) * 64 + k] = f2bf(tile[k][e]);
    }
}

// ---------------- nodes = concat([H||H2d, H||virt]) @ W_i.T (bf16 out) ----------------
__global__ __launch_bounds__(256) void nodes_kernel(
    const float* __restrict__ H, const float* __restrict__ H2d,
    const float* __restrict__ virt, const float* __restrict__ Wi,
    ushort* __restrict__ nodesb) {
    __shared__ float x[16][256];
    const int t = threadIdx.x;
    const int rbase = blockIdx.x * 16;

    for (int i = t; i < 16 * 64; i += 256) {
        int r = i >> 6, q = i & 63;
        int row = rbase + r;
        float4 v;
        if (row < NN) {
            v = (q < 32) ? ld4(H + row * 128 + q * 4) : ld4(H2d + row * 128 + (q - 32) * 4);
        } else {
            int rr = row - NN;
            v = (q < 32) ? ld4(H + rr * 128 + q * 4) : ld4(virt + (q - 32) * 4);
        }
        *reinterpret_cast<float4*>(&x[r][q * 4]) = v;
    }
    __syncthreads();

    const int j = t & 127;
    const int rg = t >> 7;
    float acc[8] = {0.f, 0.f, 0.f, 0.f, 0.f, 0.f, 0.f, 0.f};
    for (int k4 = 0; k4 < 64; ++k4) {
        float4 w = ld4(Wi + j * 256 + k4 * 4);
#pragma unroll
        for (int r = 0; r < 8; ++r) {
            float4 xv = *reinterpret_cast<const float4*>(&x[rg * 8 + r][k4 * 4]);
            acc[r] += w.x * xv.x + w.y * xv.y + w.z * xv.z + w.w * xv.w;
        }
    }
#pragma unroll
    for (int r = 0; r < 8; ++r)
        nodesb[(rbase + rg * 8 + r) * 128 + j] = f2bf(acc[r]);
}

// ---------------- fused MFMA edge pipeline, weights staged in LDS ----------------
// MODE 0: atomic scatter (fallback). MODE 1: sorted chunk + payload store.
template <int MODE>
__global__ __launch_bounds__(256, 2) void edge_kernel(
    const ushort* __restrict__ nodesb, const float* __restrict__ V,
    const float* __restrict__ Z, const float* __restrict__ Z3d,
    const int* __restrict__ E2d_idx, const float* __restrict__ E2d_feat,
    const ushort* __restrict__ featTb,
    const int* __restrict__ Edist_idx, const float* __restrict__ Edist_val,
    const ushort* __restrict__ W1c, const ushort* __restrict__ W2b,
    const ushort* __restrict__ Wmb, const float* __restrict__ b_type,
    const float* __restrict__ b_phi2, const float* __restrict__ b_msg,
    const int4* __restrict__ metaI, const float4* __restrict__ metaF,
    int p0, float* __restrict__ payloadM,
    float* __restrict__ Hout, float* __restrict__ Vout) {

    __shared__ ushort A1[TILE][264];    // phi1 input K=256 (+8 pad); aliased as hid[64][136]
    __shared__ ushort WB[128][132];     // staged weight tile (skewed rows: 2-dword offset/row)
    __shared__ float  s_bt[3][128];
    __shared__ int    s_row[TILE], s_col[TILE], s_ty[TILE], s_e2[TILE], s_vcol[TILE];
    __shared__ float  s_dist[TILE], s_dval[TILE], s_env[TILE], s_env2[TILE];
    __shared__ float  s_unit[TILE][3];

    ushort (*hid)[136] = reinterpret_cast<ushort(*)[136]>(&A1[0][0]);

    const int t = threadIdx.x;
    const int gbase = blockIdx.x * TILE;   // chunk-local base

    // ---- edge meta ----
    if (MODE == 1) {
        if (t < TILE) {
            int4 mi = metaI[p0 + gbase + t];
            s_col[t] = mi.x; s_row[t] = mi.y; s_ty[t] = mi.z; s_e2[t] = mi.w;
        } else if (t < 2 * TILE) {
            int e = t - TILE;
            float4 mf = metaF[p0 + gbase + e];
            s_dist[e] = mf.x; s_dval[e] = mf.y; s_env[e] = mf.z; s_env2[e] = mf.w;
        }
    } else {
        if (t < TILE) {
            int gpos = gbase + t;
            int eid = (gpos < NEFF) ? gpos : -1;
            int row, col, ty, e2 = 0; float dval = 0.f;
            if (eid < 0)             { ty = 1; row = -1; col = 0; }
            else if (eid < E1N)      { ty = 0; row = E2d_idx[eid]; col = E2d_idx[E1N + eid]; e2 = eid; }
            else if (eid < E1N + NN) { ty = 1; int jj = eid - E1N; row = jj; col = jj + NN; }
            else { ty = 2; int g2 = eid - E1N - NN;
                   row = Edist_idx[g2]; col = Edist_idx[E2N + g2]; dval = Edist_val[g2]; }
            int rs = (row < 0) ? 0 : row;
            float prx = Z[rs * 3], pry = Z[rs * 3 + 1], prz = Z[rs * 3 + 2];
            float pcx, pcy, pcz;
            if (col < NN) { pcx = Z[col * 3]; pcy = Z[col * 3 + 1]; pcz = Z[col * 3 + 2]; }
            else { int c = col - NN; pcx = Z3d[c * 3]; pcy = Z3d[c * 3 + 1]; pcz = Z3d[c * 3 + 2]; }
            float dx = prx - pcx, dy = pry - pcy, dz = prz - pcz;
            float dist = sqrtf(dx * dx + dy * dy + dz * dz + 1e-8f);
            float inv = 1.0f / dist;
            s_row[t] = row; s_col[t] = col; s_ty[t] = ty; s_e2[t] = e2;
            s_vcol[t] = (col < NN) ? col : -1;
            s_unit[t][0] = dx * inv; s_unit[t][1] = dy * inv; s_unit[t][2] = dz * inv;
            s_dist[t] = dist; s_dval[t] = dval;
            s_env[t] = env_of(dist); s_env2[t] = env_of(dval);
        }
    }
    for (int i = t; i < 384; i += 256) ((float*)s_bt)[i] = b_type[i];
    __syncthreads();

    // ---- phase A: stage A1 = [nodes_bf16[col] | attr] and WB <- W1c K-half 0 ----
    for (int i = t; i < TILE * 16; i += 256) {     // left 128: 16B vector gather
        int e = i >> 4, q = i & 15;
        *reinterpret_cast<uint4*>(&A1[e][q * 8]) =
            *reinterpret_cast<const uint4*>(nodesb + (size_t)s_col[e] * 128 + q * 8);
    }
    if (MODE == 1) {
        for (int i = t; i < TILE * 128; i += 256) {  // right 128: [featT | rbf(dval)]
            int e = i >> 7, k = i & 127;
            int ty = s_ty[e];
            ushort v = 0;
            if (ty == 0) { if (k < 64) v = featTb[(size_t)s_e2[e] * 64 + k]; }
            else if (ty == 2) {
                if (k >= 64) {
                    float dd = s_dval[e] - (float)(k - 64) * RBF_STEP;
                    v = f2bf(__expf(-dd * dd * RBF_INV2W2) * s_env2[e]);
                }
            }
            A1[e][128 + k] = v;
        }
    } else {
        for (int i = t; i < TILE * 128; i += 256) {
            int k = i >> 6, e = i & 63;
            int ty = s_ty[e];
            float v = 0.f;
            if (ty == 0) { if (k < 64) v = E2d_feat[(size_t)k * E1N + s_e2[e]]; }
            else if (ty == 2) {
                if (k >= 64) {
                    float dd = s_dval[e] - (float)(k - 64) * RBF_STEP;
                    v = __expf(-dd * dd * RBF_INV2W2) * s_env2[e];
                }
            }
            A1[e][128 + k] = f2bf(v);
        }
    }
    for (int i = t; i < 128 * 16; i += 256) {      // WB <- W1c[:, 0:128]
        int n = i >> 4, q = i & 15;
        *reinterpret_cast<uint4*>(&WB[n][q * 8]) =
            *reinterpret_cast<const uint4*>(W1c + (size_t)n * 256 + q * 8);
    }
    __syncthreads();

    const int w  = t >> 6, lane = t & 63;
    const int mh = w >> 1, nh = w & 1;           // wave: 32 edges x 64 channels
    const int lr = lane >> 4, lc = lane & 15;
    const int ar0 = mh * 32 + lc;

    // ---- wd A-fragments in-register: rbf(dist) for edges ar0, ar0+16 ----
    bf16x8 ra0[2], ra1[2];   // [ks]
    {
        float dA = s_dist[ar0],      eA = s_env[ar0];
        float dB = s_dist[ar0 + 16], eB = s_env[ar0 + 16];
#pragma unroll
        for (int ks = 0; ks < 2; ++ks)
#pragma unroll
            for (int j = 0; j < 8; ++j) {
                float c  = (float)(ks * 32 + lr * 8 + j) * RBF_STEP;
                float tA = dA - c, tB = dB - c;
                ra0[ks][j] = (short)f2bf(__expf(-tA * tA * RBF_INV2W2) * eA);
                ra1[ks][j] = (short)f2bf(__expf(-tB * tB * RBF_INV2W2) * eB);
            }
    }

    // ---- phi1: (64 x 256) @ W1c^T -> silu -> hid bf16 (B staged in LDS, 2 halves) ----
    f32x4 acc[2][4];
#pragma unroll
    for (int mt = 0; mt < 2; ++mt)
#pragma unroll
        for (int nt = 0; nt < 4; ++nt) acc[mt][nt] = (f32x4){0.f, 0.f, 0.f, 0.f};
#pragma unroll
    for (int ks = 0; ks < 4; ++ks) {
        bf16x8 a0 = *reinterpret_cast<const bf16x8*>(&A1[ar0][ks * 32 + lr * 8]);
        bf16x8 a1 = *reinterpret_cast<const bf16x8*>(&A1[ar0 + 16][ks * 32 + lr * 8]);
#pragma unroll
        for (int nt = 0; nt < 4; ++nt) {
            int n = nh * 64 + nt * 16 + lc;
            bf16x8 b = *reinterpret_cast<const bf16x8*>(&WB[n][ks * 32 + lr * 8]);
            acc[0][nt] = __builtin_amdgcn_mfma_f32_16x16x32_bf16(a0, b, acc[0][nt], 0, 0, 0);
            acc[1][nt] = __builtin_amdgcn_mfma_f32_16x16x32_bf16(a1, b, acc[1][nt], 0, 0, 0);
        }
    }
    __syncthreads();
    for (int i = t; i < 128 * 16; i += 256) {      // WB <- W1c[:, 128:256]
        int n = i >> 4, q = i & 15;
        *reinterpret_cast<uint4*>(&WB[n][q * 8]) =
            *reinterpret_cast<const uint4*>(W1c + (size_t)n * 256 + 128 + q * 8);
    }
    __syncthreads();
#pragma unroll
    for (int ks = 4; ks < 8; ++ks) {
        bf16x8 a0 = *reinterpret_cast<const bf16x8*>(&A1[ar0][ks * 32 + lr * 8]);
        bf16x8 a1 = *reinterpret_cast<const bf16x8*>(&A1[ar0 + 16][ks * 32 + lr * 8]);
#pragma unroll
        for (int nt = 0; nt < 4; ++nt) {
            int n = nh * 64 + nt * 16 + lc;
            bf16x8 b = *reinterpret_cast<const bf16x8*>(&WB[n][(ks - 4) * 32 + lr * 8]);
            acc[0][nt] = __builtin_amdgcn_mfma_f32_16x16x32_bf16(a0, b, acc[0][nt], 0, 0, 0);
            acc[1][nt] = __builtin_amdgcn_mfma_f32_16x16x32_bf16(a1, b, acc[1][nt], 0, 0, 0);
        }
    }
    __syncthreads();   // all A1 + WB reads complete

    // ---- silu -> hid; stage WB <- W2b slice for c=0 ----
#pragma unroll
    for (int mt = 0; mt < 2; ++mt)
#pragma unroll
        for (int nt = 0; nt < 4; ++nt)
#pragma unroll
            for (int r = 0; r < 4; ++r) {
                int e  = mh * 32 + mt * 16 + lr * 4 + r;
                int ch = nh * 64 + nt * 16 + lc;
                float x = acc[mt][nt][r] + s_bt[s_ty[e]][ch];
                hid[e][ch] = f2bf(x / (1.0f + __expf(-x)));
            }
    for (int i = t; i < 128 * 16; i += 256) {
        int n = i >> 4, q = i & 15;
        *reinterpret_cast<uint4*>(&WB[n][q * 8]) =
            *reinterpret_cast<const uint4*>(W2b + (size_t)n * 128 + q * 8);
    }
    __syncthreads();

    // ---- phi2 + wd in 3 channel-chunks of 128; m = phi*wd; emit ----
    f32x4 vgr[2][4];
#pragma unroll
    for (int c = 0; c < 3; ++c) {
        f32x4 p[2][4], g[2][4];
#pragma unroll
        for (int mt = 0; mt < 2; ++mt)
#pragma unroll
            for (int nt = 0; nt < 4; ++nt) {
                p[mt][nt] = (f32x4){0.f, 0.f, 0.f, 0.f};
                g[mt][nt] = (f32x4){0.f, 0.f, 0.f, 0.f};
            }
#pragma unroll
        for (int ks = 0; ks < 4; ++ks) {
            bf16x8 a0 = *reinterpret_cast<const bf16x8*>(&hid[ar0][ks * 32 + lr * 8]);
            bf16x8 a1 = *reinterpret_cast<const bf16x8*>(&hid[ar0 + 16][ks * 32 + lr * 8]);
#pragma unroll
            for (int nt = 0; nt < 4; ++nt) {
                int n = nh * 64 + nt * 16 + lc;
                bf16x8 b = *reinterpret_cast<const bf16x8*>(&WB[n][ks * 32 + lr * 8]);
                p[0][nt] = __builtin_amdgcn_mfma_f32_16x16x32_bf16(a0, b, p[0][nt], 0, 0, 0);
                p[1][nt] = __builtin_amdgcn_mfma_f32_16x16x32_bf16(a1, b, p[1][nt], 0, 0, 0);
            }
        }
#pragma unroll
        for (int ks = 0; ks < 2; ++ks) {
#pragma unroll
            for (int nt = 0; nt < 4; ++nt) {
                int n = c * 128 + nh * 64 + nt * 16 + lc;
                bf16x8 b = *reinterpret_cast<const bf16x8*>(Wmb + (size_t)n * 64 + ks * 32 + lr * 8);
                g[0][nt] = __builtin_amdgcn_mfma_f32_16x16x32_bf16(ra0[ks], b, g[0][nt], 0, 0, 0);
                g[1][nt] = __builtin_amdgcn_mfma_f32_16x16x32_bf16(ra1[ks], b, g[1][nt], 0, 0, 0);
            }
        }
        __syncthreads();               // done reading WB for this c
        if (c < 2) {                   // stage next c's W2b slice (overlaps epilogue)
            for (int i = t; i < 128 * 16; i += 256) {
                int n = i >> 4, q = i & 15;
                *reinterpret_cast<uint4*>(&WB[n][q * 8]) =
                    *reinterpret_cast<const uint4*>(W2b + (size_t)((c + 1) * 128 + n) * 128 + q * 8);
            }
        }
#pragma unroll
        for (int mt = 0; mt < 2; ++mt)
#pragma unroll
            for (int nt = 0; nt < 4; ++nt) {
                int d  = nh * 64 + nt * 16 + lc;
                float b2 = b_phi2[c * 128 + d];
                float bm = b_msg[c * 128 + d];
#pragma unroll
                for (int r = 0; r < 4; ++r) {
                    int e = mh * 32 + mt * 16 + lr * 4 + r;
                    float m = (p[mt][nt][r] + b2) * (g[mt][nt][r] + bm);
                    int row = s_row[e];
                    if (MODE == 1) {
                        if (row >= 0) payloadM[(size_t)(gbase + e) * 384 + c * 128 + d] = m;
                    } else {
                        if (c == 0) {
                            if (row >= 0) unsafeAtomicAdd(&Hout[(size_t)row * 128 + d], m);
                        } else if (c == 1) {
                            vgr[mt][nt][r] = m;
                        } else if (row >= 0) {
                            float vgv = vgr[mt][nt][r];
                            int vc = s_vcol[e];
                            float vx = 0.f, vy = 0.f, vz = 0.f;
                            if (vc >= 0) {
                                const float* vp = V + ((size_t)vc * 128 + d) * 3;
                                vx = vp[0]; vy = vp[1]; vz = vp[2];
                            }
                            float* vo = Vout + ((size_t)row * 128 + d) * 3;
                            unsafeAtomicAdd(vo + 0, vx * vgv + s_unit[e][0] * m);
                            unsafeAtomicAdd(vo + 1, vy * vgv + s_unit[e][1] * m);
                            unsafeAtomicAdd(vo + 2, vz * vgv + s_unit[e][2] * m);
                        }
                    }
                }
            }
        __syncthreads();               // WB(c+1) staged before next iteration reads it
    }
}

// ---------------- reduce: accumulate chunk payload into output (+V gather) ----------------
__global__ __launch_bounds__(256) void reduce_kernel(
    const float* __restrict__ payloadM, const float4* __restrict__ payloadU,
    const float* __restrict__ V, const int* __restrict__ start,
    const int* __restrict__ chunk_r0, int ci, int p0, int p1,
    float* __restrict__ Hout, float* __restrict__ Vout) {
    const int t = threadIdx.x;
    const int rbase = chunk_r0[ci] + blockIdx.x * 8;
    const bool hside = (t < 128);
    const int d = hside ? t : (t - 128);
    for (int nr = 0; nr < 8; ++nr) {
        int r = rbase + nr;
        if (r >= NN) return;
        int s0 = start[r], s1 = start[r + 1];
        if (s0 >= p1) return;            // rows sorted; nothing further in chunk
        int a = (s0 > p0) ? s0 : p0;
        int b = (s1 < p1) ? s1 : p1;
        if (a >= b) continue;            // row not in this chunk
        if (hside) {
            float acc = 0.f;
            for (int i = a; i < b; ++i) acc += payloadM[(size_t)(i - p0) * 384 + d];
            float* ptr = &Hout[(size_t)r * 128 + d];
            float o = *ptr + acc;
            if (s1 <= p1) o = fminf(fmaxf(o, -100.f), 100.f);
            *ptr = o;
        } else {
            float ax = 0.f, ay = 0.f, az = 0.f;
            for (int i = a; i < b; ++i) {
                const float* pm = payloadM + (size_t)(i - p0) * 384;
                float vg = pm[128 + d], rg = pm[256 + d];
                float4 u = payloadU[i];
                int vc = __float_as_int(u.w);
                if (vc >= 0) {
                    const float* vp = V + (size_t)vc * 384 + d * 3;
                    ax += vg * vp[0]; ay += vg * vp[1]; az += vg * vp[2];
                }
                ax += rg * u.x; ay += rg * u.y; az += rg * u.z;
            }
            float* vo = Vout + (size_t)r * 384 + d * 3;
            float ox = vo[0] + ax, oy = vo[1] + ay, oz = vo[2] + az;
            if (s1 <= p1) {
                ox = fminf(fmaxf(ox, -100.f), 100.f);
                oy = fminf(fmaxf(oy, -100.f), 100.f);
                oz = fminf(fmaxf(oz, -100.f), 100.f);
            }
            vo[0] = ox; vo[1] = oy; vo[2] = oz;
        }
    }
}

extern "C" void kernel_launch(void* const* d_in, const int* in_sizes, int n_in,
                              void* d_out, int out_size, void* d_ws, size_t ws_size,
                              hipStream_t stream) {
    const float* H         = (const float*)d_in[0];
    const float* V         = (const float*)d_in[1];
    const float* Z         = (const float*)d_in[2];
    const float* H2d       = (const float*)d_in[4];
    const int*   E2d_idx   = (const int*)d_in[6];
    const float* E2d_feat  = (const float*)d_in[7];
    const float* Z3d       = (const float*)d_in[8];
    const int*   Edist_idx = (const int*)d_in[10];
    const float* Edist_val = (const float*)d_in[11];
    const float* virt      = (const float*)d_in[12];
    const float* et        = (const float*)d_in[13];
    const float* W_rbf     = (const float*)d_in[14];
    const float* W_e2d     = (const float*)d_in[15];
    const float* W_i       = (const float*)d_in[16];
    const float* W_phi1    = (const float*)d_in[17];
    const float* b_phi1    = (const float*)d_in[18];
    const float* W_phi2    = (const float*)d_in[19];
    const float* b_phi2    = (const float*)d_in[20];
    const float* W_msg     = (const float*)d_in[21];
    const float* b_msg     = (const float*)d_in[22];

    ushort* nodesb  = (ushort*)d_ws;                 // 40000*128 bf16
    ushort* W1c     = nodesb + 5120000;              // (128,256)
    ushort* W2b     = W1c + 32768;                   // (384,128)
    ushort* Wmb     = W2b + 49152;                   // (384,64)
    float*  b_type  = (float*)(Wmb + 24576);         // (3,128)
    ushort* featTb  = (ushort*)(b_type + 384);       // (E1N,64) bf16 = 12.8 MB
    int*    hist    = (int*)(featTb + (size_t)E1N * 64);
    int*    cursor  = hist + NN;
    int*    start   = cursor + NN;                   // NN+1
    int*    order   = start + NN + 1;                // NPAD
    int*    chunk_r0= order + NPAD;                  // 64
    int4*   metaI   = (int4*)(((size_t)(chunk_r0 + 64) + 15) & ~(size_t)15);
    float4* metaF   = (float4*)(metaI + NPAD);
    float4* payloadU= metaF + NPAD;

    size_t fixed = (size_t)((char*)(payloadU + NPAD) - (char*)d_ws);
    size_t poff  = (fixed + 255) & ~(size_t)255;
    float* payloadM = (float*)((char*)d_ws + poff);
    size_t avail = (ws_size > poff) ? (ws_size - poff) : 0;
    long long cap_ll = (long long)(avail / 1536) / TILE * TILE;   // 384 f32 per edge
    int cap = (cap_ll > (long long)NPAD) ? NPAD : (int)cap_ll;
    const bool big = (cap >= 4096);

    float* Hout = (float*)d_out;
    float* Vout = Hout + (size_t)NN * 128;

    hipMemsetAsync(d_out, 0, (size_t)out_size * sizeof(float), stream);
    prep_kernel<<<(32768 + 49152 + 24576 + 384 + 255) / 256, 256, 0, stream>>>(
        W_phi1, b_phi1, W_e2d, W_rbf, W_phi2, W_msg, et, W1c, W2b, Wmb, b_type);
    nodes_kernel<<<(2 * NN) / 16, 256, 0, stream>>>(H, H2d, virt, W_i, nodesb);

    if (big) {
        hipMemsetAsync(hist, 0, NN * sizeof(int), stream);
        featT_kernel<<<(E1N + 63) / 64, 256, 0, stream>>>(E2d_feat, featTb);
        hist_kernel<<<(NEFF + 255) / 256, 256, 0, stream>>>(E2d_idx, Edist_idx, hist);
        scan_kernel<<<1, 1024, 0, stream>>>(hist, start, cursor);
        scatter_kernel<<<(NEFF + 255) / 256, 256, 0, stream>>>(E2d_idx, Edist_idx, cursor, order);
        meta_kernel<<<(NPAD + 255) / 256, 256, 0, stream>>>(
            order, E2d_idx, Edist_idx, Edist_val, Z, Z3d, metaI, metaF, payloadU);
        int bpc = cap / TILE;
        int nch = (NBLK + bpc - 1) / bpc;
        chunkrow_kernel<<<1, 64, 0, stream>>>(order, E2d_idx, Edist_idx, cap, nch, chunk_r0);
        int rbound = (NN < cap + 1) ? NN : (cap + 1);
        int rgrid  = (rbound + 7) / 8;
        for (int ci = 0; ci < nch; ++ci) {
            int b0 = ci * bpc;
            int nb = ((NBLK - b0) < bpc) ? (NBLK - b0) : bpc;
            int p0 = b0 * TILE;
            int p1 = p0 + nb * TILE; if (p1 > NEFF) p1 = NEFF;
            edge_kernel<1><<<nb, 256, 0, stream>>>(
                nodesb, V, Z, Z3d, E2d_idx, E2d_feat, featTb, Edist_idx, Edist_val,
                W1c, W2b, Wmb, b_type, b_phi2, b_msg, metaI, metaF, p0, payloadM,
                Hout, Vout);
            reduce_kernel<<<rgrid, 256, 0, stream>>>(payloadM, payloadU, V, start,
                                                     chunk_r0, ci, p0, p1, Hout, Vout);
        }
    } else {
        edge_kernel<0><<<NBLK, 256, 0, stream>>>(
            nodesb, V, Z, Z3d, E2d_idx, E2d_feat, featTb, Edist_idx, Edist_val,
            W1c, W2b, Wmb, b_type, b_phi2, b_msg, metaI, metaF, 0, payloadM,
            Hout, Vout);
    }
}